// Round 1
// baseline (1482.987 us; speedup 1.0000x reference)
//
#include <hip/hip_runtime.h>
#include <hip/hip_bf16.h>

// GraphSAGE forward, fp32 baseline.
// Restructure: aggr(x) @ Wn == aggr(x @ Wn)  -> aggregate in 256-dim space.
// Per layer: Y = H_in @ [Wn | Ws]  (N x 512), then
//   h_out[v] = relu( (sum_{e:dst=v} Yn[src[e]]) / max(deg[v],1) + Ys[v] + b )

#define HID 256
#define NCOL 512   // concatenated output width per layer

// ---------------- weight pack: Wcat[k][0:256]=Wn[k], Wcat[k][256:512]=Ws[k]
__global__ void pack_kernel(const float* __restrict__ Wn, const float* __restrict__ Ws,
                            float* __restrict__ Wcat, int K) {
    int gid = blockIdx.x * 256 + threadIdx.x;
    if (gid >= K * NCOL) return;
    int k = gid >> 9, j = gid & (NCOL - 1);
    Wcat[gid] = (j < HID) ? Wn[k * HID + j] : Ws[k * HID + (j - HID)];
}

// ---------------- degree histogram
__global__ void deg_kernel(const int* __restrict__ dst, float* __restrict__ deg, int n_edges) {
    int e = blockIdx.x * 256 + threadIdx.x;
    if (e < n_edges) atomicAdd(&deg[dst[e]], 1.0f);
}

// ---------------- fp32 tiled GEMM: C[M,N] = A[M,K] @ B[K,N], row-major, N=512, K%16==0
__global__ __launch_bounds__(256) void gemm64(const float* __restrict__ A,
                                              const float* __restrict__ B,
                                              float* __restrict__ C,
                                              int M, int K, int N) {
    __shared__ float As[16][65];   // transposed A tile, padded
    __shared__ float Bs[16][68];   // padded, 16B-aligned rows
    int tid = threadIdx.x;
    int ty = tid >> 4, tx = tid & 15;
    int m0 = blockIdx.y * 64, n0 = blockIdx.x * 64;
    float acc[4][4] = {};
    int am = tid >> 2, ak = (tid & 3) << 2;   // A tile: 64 rows x 16 k, float4 along K
    int bkr = ty, bn4 = tx << 2;              // B tile: 16 k x 64 n, float4 along N

    for (int k0 = 0; k0 < K; k0 += 16) {
        float4 av = make_float4(0.f, 0.f, 0.f, 0.f);
        int arow = m0 + am;
        if (arow < M) av = *(const float4*)(A + (size_t)arow * K + k0 + ak);
        float4 bv = *(const float4*)(B + (size_t)(k0 + bkr) * N + n0 + bn4);
        __syncthreads();
        As[ak + 0][am] = av.x; As[ak + 1][am] = av.y;
        As[ak + 2][am] = av.z; As[ak + 3][am] = av.w;
        *(float4*)&Bs[bkr][bn4] = bv;
        __syncthreads();
#pragma unroll
        for (int kk = 0; kk < 16; ++kk) {
            float a[4], b[4];
#pragma unroll
            for (int i = 0; i < 4; ++i) a[i] = As[kk][(ty << 2) + i];
#pragma unroll
            for (int j = 0; j < 4; ++j) b[j] = Bs[kk][(tx << 2) + j];
#pragma unroll
            for (int i = 0; i < 4; ++i)
#pragma unroll
                for (int j = 0; j < 4; ++j) acc[i][j] += a[i] * b[j];
        }
    }
#pragma unroll
    for (int i = 0; i < 4; ++i) {
        int row = m0 + (ty << 2) + i;
        if (row < M) {
            float4 r = make_float4(acc[i][0], acc[i][1], acc[i][2], acc[i][3]);
            *(float4*)(C + (size_t)row * N + n0 + (tx << 2)) = r;
        }
    }
}

// ---------------- edge scatter: aggr[dst] += Yn[src]  (cols 0..255 of Y)
__global__ void scatter_kernel(const float* __restrict__ Y,
                               const int* __restrict__ src, const int* __restrict__ dst,
                               float* __restrict__ aggr, int n_edges) {
    int gid = blockIdx.x * 256 + threadIdx.x;
    int e = gid >> 6, q = gid & 63;           // 64 threads/edge, float4 each
    if (e >= n_edges) return;
    int s = src[e], d = dst[e];
    float4 v = *(const float4*)(Y + (size_t)s * NCOL + (q << 2));
    float* o = aggr + (size_t)d * HID + (q << 2);
    atomicAdd(o + 0, v.x); atomicAdd(o + 1, v.y);
    atomicAdd(o + 2, v.z); atomicAdd(o + 3, v.w);
}

// ---------------- combine: h = relu(aggr/deg + Ys + b)
__global__ void combine_kernel(const float* __restrict__ aggr, const float* __restrict__ Y,
                               const float* __restrict__ deg, const float* __restrict__ bias,
                               float* __restrict__ h, int n_nodes) {
    int gid = blockIdx.x * 256 + threadIdx.x;
    int v = gid >> 6, q = gid & 63;
    if (v >= n_nodes) return;
    float invd = 1.0f / fmaxf(deg[v], 1.0f);
    float4 a = *(const float4*)(aggr + (size_t)v * HID + (q << 2));
    float4 s = *(const float4*)(Y + (size_t)v * NCOL + HID + (q << 2));
    float4 b = *(const float4*)(bias + (q << 2));
    float4 r;
    r.x = fmaxf(a.x * invd + s.x + b.x, 0.f);
    r.y = fmaxf(a.y * invd + s.y + b.y, 0.f);
    r.z = fmaxf(a.z * invd + s.z + b.z, 0.f);
    r.w = fmaxf(a.w * invd + s.w + b.w, 0.f);
    *(float4*)(h + (size_t)v * HID + (q << 2)) = r;
}

// ---------------- segmented mean-pool (batch sorted): run-length accumulate per 64-node chunk
__global__ void pool_kernel(const float* __restrict__ h, const int* __restrict__ batch,
                            float* __restrict__ pooled, float* __restrict__ cnt, int n_nodes) {
    int f = threadIdx.x;                     // 256 features
    int v0 = blockIdx.x * 64;
    int vend = min(v0 + 64, n_nodes);
    if (v0 >= n_nodes) return;
    int cur = batch[v0];
    float acc = 0.f, ac = 0.f;
    for (int v = v0; v < vend; ++v) {
        int g = batch[v];
        if (g != cur) {
            atomicAdd(&pooled[cur * HID + f], acc);
            if (f == 0) atomicAdd(&cnt[cur], ac);
            acc = 0.f; ac = 0.f; cur = g;
        }
        acc += h[(size_t)v * HID + f];
        ac += 1.0f;
    }
    atomicAdd(&pooled[cur * HID + f], acc);
    if (f == 0) atomicAdd(&cnt[cur], ac);
}

// ---------------- MLP head: out[g] = relu(pooled_mean @ fc1w + fc1b) @ fc2w + fc2b
__global__ void head_kernel(const float* __restrict__ pooled, const float* __restrict__ cnt,
                            const float* __restrict__ fc1w, const float* __restrict__ fc1b,
                            const float* __restrict__ fc2w, const float* __restrict__ fc2b,
                            float* __restrict__ out) {
    int g = blockIdx.x, j = threadIdx.x;     // 128 threads
    __shared__ float p[256];
    __shared__ float hid[128];
    float inv = 1.0f / fmaxf(cnt[g], 1.0f);
    p[j] = pooled[g * HID + j] * inv;
    p[j + 128] = pooled[g * HID + 128 + j] * inv;
    __syncthreads();
    float a = fc1b[j];
    for (int f = 0; f < 256; ++f) a += p[f] * fc1w[f * 128 + j];
    hid[j] = fmaxf(a, 0.f);
    __syncthreads();
    if (j < 2) {
        float o = fc2b[j];
        for (int t = 0; t < 128; ++t) o += hid[t] * fc2w[t * 2 + j];
        out[g * 2 + j] = o;
    }
}

extern "C" void kernel_launch(void* const* d_in, const int* in_sizes, int n_in,
                              void* d_out, int out_size, void* d_ws, size_t ws_size,
                              hipStream_t stream) {
    const float* x    = (const float*)d_in[0];
    const int*   ei   = (const int*)d_in[1];
    const int*   batch= (const int*)d_in[2];
    const float* W1n  = (const float*)d_in[3];
    const float* W1s  = (const float*)d_in[4];
    const float* b1   = (const float*)d_in[5];
    const float* W2n  = (const float*)d_in[6];
    const float* W2s  = (const float*)d_in[7];
    const float* b2   = (const float*)d_in[8];
    const float* fc1w = (const float*)d_in[9];
    const float* fc1b = (const float*)d_in[10];
    const float* fc2w = (const float*)d_in[11];
    const float* fc2b = (const float*)d_in[12];
    float* out = (float*)d_out;

    const int n_nodes = in_sizes[2];
    const int n_edges = in_sizes[1] / 2;
    const int in_dim  = in_sizes[0] / n_nodes;   // 512
    const int* src = ei;
    const int* dst = ei + n_edges;

    // workspace layout (floats), 64-float aligned
    float* ws = (float*)d_ws;
    size_t cur = 0;
    auto alloc = [&](size_t nflt) { size_t o = cur; cur = (cur + nflt + 63) & ~(size_t)63; return o; };
    size_t o_deg  = alloc((size_t)n_nodes);
    size_t o_w1   = alloc((size_t)in_dim * NCOL);
    size_t o_w2   = alloc((size_t)HID * NCOL);
    size_t o_y    = alloc((size_t)n_nodes * NCOL);
    size_t o_aggr = alloc((size_t)n_nodes * HID);
    size_t o_h    = alloc((size_t)n_nodes * HID);
    size_t o_pool = alloc((size_t)16 * HID);
    size_t o_cnt  = alloc((size_t)16);
    (void)ws_size;

    float* deg   = ws + o_deg;
    float* w1cat = ws + o_w1;
    float* w2cat = ws + o_w2;
    float* Y     = ws + o_y;
    float* aggr  = ws + o_aggr;
    float* h     = ws + o_h;
    float* pooled= ws + o_pool;
    float* cnt   = ws + o_cnt;

    // zero the accumulated buffers (ws is poisoned before every call)
    hipMemsetAsync(deg, 0, (size_t)n_nodes * 4, stream);
    hipMemsetAsync(aggr, 0, (size_t)n_nodes * HID * 4, stream);
    hipMemsetAsync(pooled, 0, (size_t)(16 * HID + 16) * 4, stream);  // pooled + cnt contiguous

    // pack weights
    pack_kernel<<<(in_dim * NCOL + 255) / 256, 256, 0, stream>>>(W1n, W1s, w1cat, in_dim);
    pack_kernel<<<(HID * NCOL + 255) / 256, 256, 0, stream>>>(W2n, W2s, w2cat, HID);

    // degrees
    deg_kernel<<<(n_edges + 255) / 256, 256, 0, stream>>>(dst, deg, n_edges);

    dim3 gemm_grid(NCOL / 64, (n_nodes + 63) / 64);

    // ---- layer 1
    gemm64<<<gemm_grid, 256, 0, stream>>>(x, w1cat, Y, n_nodes, in_dim, NCOL);
    scatter_kernel<<<(n_edges * 64 + 255) / 256, 256, 0, stream>>>(Y, src, dst, aggr, n_edges);
    combine_kernel<<<(n_nodes * 64 + 255) / 256, 256, 0, stream>>>(aggr, Y, deg, b1, h, n_nodes);

    // ---- layer 2
    hipMemsetAsync(aggr, 0, (size_t)n_nodes * HID * 4, stream);
    gemm64<<<gemm_grid, 256, 0, stream>>>(h, w2cat, Y, n_nodes, HID, NCOL);
    scatter_kernel<<<(n_edges * 64 + 255) / 256, 256, 0, stream>>>(Y, src, dst, aggr, n_edges);
    combine_kernel<<<(n_nodes * 64 + 255) / 256, 256, 0, stream>>>(aggr, Y, deg, b2, h, n_nodes);

    // ---- pool + head
    pool_kernel<<<(n_nodes + 63) / 64, 256, 0, stream>>>(h, batch, pooled, cnt, n_nodes);
    head_kernel<<<16, 128, 0, stream>>>(pooled, cnt, fc1w, fc1b, fc2w, fc2b, out);
}

// Round 2
// 477.668 us; speedup vs baseline: 3.1046x; 3.1046x over previous
//
#include <hip/hip_runtime.h>
#include <hip/hip_bf16.h>

// GraphSAGE forward, fp32. R1: CSR-by-dst gather replaces atomic scatter.
// Restructure: aggr(x) @ Wn == aggr(x @ Wn)  -> aggregate in 256-dim space.
// Per layer: Y = H_in @ [Wn | Ws]  (N x 512), then fused gather:
//   h_out[v] = relu( (sum_{e in CSR[v]} Yn[eidx[e]]) / max(deg,1) + Ys[v] + b )

#define HID 256
#define NCOL 512   // concatenated output width per layer

// ---------------- weight pack: Wcat[k][0:256]=Wn[k], Wcat[k][256:512]=Ws[k]
__global__ void pack_kernel(const float* __restrict__ Wn, const float* __restrict__ Ws,
                            float* __restrict__ Wcat, int K) {
    int gid = blockIdx.x * 256 + threadIdx.x;
    if (gid >= K * NCOL) return;
    int k = gid >> 9, j = gid & (NCOL - 1);
    Wcat[gid] = (j < HID) ? Wn[k * HID + j] : Ws[k * HID + (j - HID)];
}

// ---------------- int degree histogram (by dst)
__global__ void degi_kernel(const int* __restrict__ dst, int* __restrict__ degi, int n_edges) {
    int e = blockIdx.x * 256 + threadIdx.x;
    if (e < n_edges) atomicAdd(&degi[dst[e]], 1);
}

// ---------------- single-block exclusive scan over degi -> off[0..n], off[n]=total
__global__ __launch_bounds__(1024) void scan_kernel(const int* __restrict__ degi,
                                                    int* __restrict__ off, int n) {
    __shared__ int carry;
    __shared__ int tmp[1024];
    if (threadIdx.x == 0) carry = 0;
    __syncthreads();
    for (int base = 0; base < n; base += 1024) {
        int i = base + threadIdx.x;
        int v = (i < n) ? degi[i] : 0;
        tmp[threadIdx.x] = v;
        __syncthreads();
        for (int s = 1; s < 1024; s <<= 1) {
            int t = (threadIdx.x >= s) ? tmp[threadIdx.x - s] : 0;
            __syncthreads();
            tmp[threadIdx.x] += t;
            __syncthreads();
        }
        if (i < n) off[i] = carry + tmp[threadIdx.x] - v;   // exclusive
        __syncthreads();
        if (threadIdx.x == 1023) carry += tmp[1023];
        __syncthreads();
    }
    if (threadIdx.x == 0) off[n] = carry;
}

__global__ void copy_int_kernel(const int* __restrict__ a, int* __restrict__ b, int n) {
    int i = blockIdx.x * 256 + threadIdx.x;
    if (i < n) b[i] = a[i];
}

// ---------------- CSR fill: eidx[pos] = src[e], pos = cursor[dst[e]]++
__global__ void fill_kernel(const int* __restrict__ src, const int* __restrict__ dst,
                            int* __restrict__ cursor, int* __restrict__ eidx, int n_edges) {
    int e = blockIdx.x * 256 + threadIdx.x;
    if (e < n_edges) {
        int p = atomicAdd(&cursor[dst[e]], 1);
        eidx[p] = src[e];
    }
}

// ---------------- fp32 tiled GEMM: C[M,N] = A[M,K] @ B[K,N], row-major, N=512, K%16==0
__global__ __launch_bounds__(256) void gemm64(const float* __restrict__ A,
                                              const float* __restrict__ B,
                                              float* __restrict__ C,
                                              int M, int K, int N) {
    __shared__ float As[16][65];   // transposed A tile, padded
    __shared__ float Bs[16][68];   // padded, 16B-aligned rows
    int tid = threadIdx.x;
    int ty = tid >> 4, tx = tid & 15;
    int m0 = blockIdx.y * 64, n0 = blockIdx.x * 64;
    float acc[4][4] = {};
    int am = tid >> 2, ak = (tid & 3) << 2;   // A tile: 64 rows x 16 k, float4 along K
    int bkr = ty, bn4 = tx << 2;              // B tile: 16 k x 64 n, float4 along N

    for (int k0 = 0; k0 < K; k0 += 16) {
        float4 av = make_float4(0.f, 0.f, 0.f, 0.f);
        int arow = m0 + am;
        if (arow < M) av = *(const float4*)(A + (size_t)arow * K + k0 + ak);
        float4 bv = *(const float4*)(B + (size_t)(k0 + bkr) * N + n0 + bn4);
        __syncthreads();
        As[ak + 0][am] = av.x; As[ak + 1][am] = av.y;
        As[ak + 2][am] = av.z; As[ak + 3][am] = av.w;
        *(float4*)&Bs[bkr][bn4] = bv;
        __syncthreads();
#pragma unroll
        for (int kk = 0; kk < 16; ++kk) {
            float a[4], b[4];
#pragma unroll
            for (int i = 0; i < 4; ++i) a[i] = As[kk][(ty << 2) + i];
#pragma unroll
            for (int j = 0; j < 4; ++j) b[j] = Bs[kk][(tx << 2) + j];
#pragma unroll
            for (int i = 0; i < 4; ++i)
#pragma unroll
                for (int j = 0; j < 4; ++j) acc[i][j] += a[i] * b[j];
        }
    }
#pragma unroll
    for (int i = 0; i < 4; ++i) {
        int row = m0 + (ty << 2) + i;
        if (row < M) {
            float4 r = make_float4(acc[i][0], acc[i][1], acc[i][2], acc[i][3]);
            *(float4*)(C + (size_t)row * N + n0 + (tx << 2)) = r;
        }
    }
}

// ---------------- fused gather + combine: one 64-lane wave per node
// h[v] = relu( (sum_{e} Yn[eidx[e]]) / max(deg,1) + Ys[v] + b )
__global__ __launch_bounds__(256) void gather_kernel(const float* __restrict__ Y,
                                                     const int* __restrict__ off,
                                                     const int* __restrict__ eidx,
                                                     const float* __restrict__ bias,
                                                     float* __restrict__ h, int n_nodes) {
    int tid = threadIdx.x;
    int v = blockIdx.x * 4 + (tid >> 6);
    if (v >= n_nodes) return;
    int q4 = (tid & 63) << 2;
    int e0 = off[v], e1 = off[v + 1];
    float4 acc = make_float4(0.f, 0.f, 0.f, 0.f);
    for (int e = e0; e < e1; ++e) {
        int s = eidx[e];
        float4 y = *(const float4*)(Y + (size_t)s * NCOL + q4);
        acc.x += y.x; acc.y += y.y; acc.z += y.z; acc.w += y.w;
    }
    float invd = 1.0f / fmaxf((float)(e1 - e0), 1.0f);
    float4 s = *(const float4*)(Y + (size_t)v * NCOL + HID + q4);
    float4 b = *(const float4*)(bias + q4);
    float4 r;
    r.x = fmaxf(acc.x * invd + s.x + b.x, 0.f);
    r.y = fmaxf(acc.y * invd + s.y + b.y, 0.f);
    r.z = fmaxf(acc.z * invd + s.z + b.z, 0.f);
    r.w = fmaxf(acc.w * invd + s.w + b.w, 0.f);
    *(float4*)(h + (size_t)v * HID + q4) = r;
}

// ---------------- segmented mean-pool (batch sorted): run-length accumulate per 64-node chunk
__global__ void pool_kernel(const float* __restrict__ h, const int* __restrict__ batch,
                            float* __restrict__ pooled, float* __restrict__ cnt, int n_nodes) {
    int f = threadIdx.x;                     // 256 features
    int v0 = blockIdx.x * 64;
    int vend = min(v0 + 64, n_nodes);
    if (v0 >= n_nodes) return;
    int cur = batch[v0];
    float acc = 0.f, ac = 0.f;
    for (int v = v0; v < vend; ++v) {
        int g = batch[v];
        if (g != cur) {
            atomicAdd(&pooled[cur * HID + f], acc);
            if (f == 0) atomicAdd(&cnt[cur], ac);
            acc = 0.f; ac = 0.f; cur = g;
        }
        acc += h[(size_t)v * HID + f];
        ac += 1.0f;
    }
    atomicAdd(&pooled[cur * HID + f], acc);
    if (f == 0) atomicAdd(&cnt[cur], ac);
}

// ---------------- MLP head: out[g] = relu(pooled_mean @ fc1w + fc1b) @ fc2w + fc2b
__global__ void head_kernel(const float* __restrict__ pooled, const float* __restrict__ cnt,
                            const float* __restrict__ fc1w, const float* __restrict__ fc1b,
                            const float* __restrict__ fc2w, const float* __restrict__ fc2b,
                            float* __restrict__ out) {
    int g = blockIdx.x, j = threadIdx.x;     // 128 threads
    __shared__ float p[256];
    __shared__ float hid[128];
    float inv = 1.0f / fmaxf(cnt[g], 1.0f);
    p[j] = pooled[g * HID + j] * inv;
    p[j + 128] = pooled[g * HID + 128 + j] * inv;
    __syncthreads();
    float a = fc1b[j];
    for (int f = 0; f < 256; ++f) a += p[f] * fc1w[f * 128 + j];
    hid[j] = fmaxf(a, 0.f);
    __syncthreads();
    if (j < 2) {
        float o = fc2b[j];
        for (int t = 0; t < 128; ++t) o += hid[t] * fc2w[t * 2 + j];
        out[g * 2 + j] = o;
    }
}

extern "C" void kernel_launch(void* const* d_in, const int* in_sizes, int n_in,
                              void* d_out, int out_size, void* d_ws, size_t ws_size,
                              hipStream_t stream) {
    const float* x    = (const float*)d_in[0];
    const int*   ei   = (const int*)d_in[1];
    const int*   batch= (const int*)d_in[2];
    const float* W1n  = (const float*)d_in[3];
    const float* W1s  = (const float*)d_in[4];
    const float* b1   = (const float*)d_in[5];
    const float* W2n  = (const float*)d_in[6];
    const float* W2s  = (const float*)d_in[7];
    const float* b2   = (const float*)d_in[8];
    const float* fc1w = (const float*)d_in[9];
    const float* fc1b = (const float*)d_in[10];
    const float* fc2w = (const float*)d_in[11];
    const float* fc2b = (const float*)d_in[12];
    float* out = (float*)d_out;

    const int n_nodes = in_sizes[2];
    const int n_edges = in_sizes[1] / 2;
    const int in_dim  = in_sizes[0] / n_nodes;   // 512
    const int* src = ei;
    const int* dst = ei + n_edges;

    // workspace layout, 256B-aligned slices (elements are 4B)
    char* wsb = (char*)d_ws;
    size_t cur = 0;
    auto alloc = [&](size_t nbytes) { size_t o = cur; cur = (cur + nbytes + 255) & ~(size_t)255; return o; };
    size_t o_degi = alloc((size_t)n_nodes * 4);
    size_t o_off  = alloc((size_t)(n_nodes + 1) * 4);
    size_t o_cur  = alloc((size_t)n_nodes * 4);
    size_t o_eidx = alloc((size_t)n_edges * 4);
    size_t o_w1   = alloc((size_t)in_dim * NCOL * 4);
    size_t o_w2   = alloc((size_t)HID * NCOL * 4);
    size_t o_y    = alloc((size_t)n_nodes * NCOL * 4);
    size_t o_h    = alloc((size_t)n_nodes * HID * 4);
    size_t o_pool = alloc((size_t)16 * HID * 4 + 16 * 4);  // pooled + cnt contiguous
    (void)ws_size;

    int*   degi   = (int*)(wsb + o_degi);
    int*   off    = (int*)(wsb + o_off);
    int*   cursor = (int*)(wsb + o_cur);
    int*   eidx   = (int*)(wsb + o_eidx);
    float* w1cat  = (float*)(wsb + o_w1);
    float* w2cat  = (float*)(wsb + o_w2);
    float* Y      = (float*)(wsb + o_y);
    float* h      = (float*)(wsb + o_h);
    float* pooled = (float*)(wsb + o_pool);
    float* cnt    = pooled + 16 * HID;

    // zero accumulated buffers (ws is poisoned before every call)
    hipMemsetAsync(degi, 0, (size_t)n_nodes * 4, stream);
    hipMemsetAsync(pooled, 0, (size_t)(16 * HID + 16) * 4, stream);

    // ---- CSR build (by dst)
    degi_kernel<<<(n_edges + 255) / 256, 256, 0, stream>>>(dst, degi, n_edges);
    scan_kernel<<<1, 1024, 0, stream>>>(degi, off, n_nodes);
    copy_int_kernel<<<(n_nodes + 255) / 256, 256, 0, stream>>>(off, cursor, n_nodes);
    fill_kernel<<<(n_edges + 255) / 256, 256, 0, stream>>>(src, dst, cursor, eidx, n_edges);

    // ---- pack weights
    pack_kernel<<<(in_dim * NCOL + 255) / 256, 256, 0, stream>>>(W1n, W1s, w1cat, in_dim);
    pack_kernel<<<(HID * NCOL + 255) / 256, 256, 0, stream>>>(W2n, W2s, w2cat, HID);

    dim3 gemm_grid(NCOL / 64, (n_nodes + 63) / 64);
    int gather_blocks = (n_nodes + 3) / 4;

    // ---- layer 1
    gemm64<<<gemm_grid, 256, 0, stream>>>(x, w1cat, Y, n_nodes, in_dim, NCOL);
    gather_kernel<<<gather_blocks, 256, 0, stream>>>(Y, off, eidx, b1, h, n_nodes);

    // ---- layer 2
    gemm64<<<gemm_grid, 256, 0, stream>>>(h, w2cat, Y, n_nodes, HID, NCOL);
    gather_kernel<<<gather_blocks, 256, 0, stream>>>(Y, off, eidx, b2, h, n_nodes);

    // ---- pool + head
    pool_kernel<<<(n_nodes + 63) / 64, 256, 0, stream>>>(h, batch, pooled, cnt, n_nodes);
    head_kernel<<<16, 128, 0, stream>>>(pooled, cnt, fc1w, fc1b, fc2w, fc2b, out);
}

// Round 3
// 312.511 us; speedup vs baseline: 4.7454x; 1.5285x over previous
//
#include <hip/hip_runtime.h>
#include <hip/hip_bf16.h>

// GraphSAGE forward. R2: bf16 MFMA GEMM (16x16x32, 128x128 tile, global_load_lds
// staging with XOR unit-swizzle), fp32 accumulate/epilogue. CSR gather from R1.
// Per layer: Y = H_in @ [Wn | Ws]  (N x 512, fp32 out), then fused gather:
//   h_out[v] = bf16( relu( (sum_{e in CSR[v]} Yn[eidx[e]]) / max(deg,1) + Ys[v] + b ) )

#define HID 256
#define NCOL 512

typedef __bf16 bf16x8 __attribute__((ext_vector_type(8)));
typedef float floatx4 __attribute__((ext_vector_type(4)));
typedef unsigned int u32;
typedef const u32 __attribute__((address_space(1)))* gp_t;
typedef u32 __attribute__((address_space(3)))* lp_t;

__device__ __forceinline__ ushort f2bf(float f) {   // round-to-nearest-even
    unsigned u = __float_as_uint(f);
    u += 0x7fffu + ((u >> 16) & 1u);
    return (ushort)(u >> 16);
}
__device__ __forceinline__ float bf2f(ushort b) {
    return __uint_as_float(((unsigned)b) << 16);
}

// ---------------- f32 -> bf16 bulk convert (n4 = n/4)
__global__ void cvt_kernel(const float* __restrict__ in, ushort* __restrict__ out, int n4) {
    int i = blockIdx.x * 256 + threadIdx.x;
    if (i >= n4) return;
    float4 v = ((const float4*)in)[i];
    ushort4 o;
    o.x = f2bf(v.x); o.y = f2bf(v.y); o.z = f2bf(v.z); o.w = f2bf(v.w);
    ((ushort4*)out)[i] = o;
}

// ---------------- weight pack+transpose: WT[n][k] bf16, n<256 -> Wn[k][n], else Ws[k][n-256]
__global__ void packT_kernel(const float* __restrict__ Wn, const float* __restrict__ Ws,
                             ushort* __restrict__ WT, int K) {
    int gid = blockIdx.x * 256 + threadIdx.x;
    if (gid >= NCOL * K) return;
    int n = gid / K, k = gid - n * K;
    float v = (n < HID) ? Wn[k * HID + n] : Ws[k * HID + (n - HID)];
    WT[gid] = f2bf(v);
}

// ---------------- int degree histogram (by dst)
__global__ void degi_kernel(const int* __restrict__ dst, int* __restrict__ degi, int n_edges) {
    int e = blockIdx.x * 256 + threadIdx.x;
    if (e < n_edges) atomicAdd(&degi[dst[e]], 1);
}

// ---------------- single-block exclusive scan over degi -> off[0..n], off[n]=total
__global__ __launch_bounds__(1024) void scan_kernel(const int* __restrict__ degi,
                                                    int* __restrict__ off, int n) {
    __shared__ int carry;
    __shared__ int tmp[1024];
    if (threadIdx.x == 0) carry = 0;
    __syncthreads();
    for (int base = 0; base < n; base += 1024) {
        int i = base + threadIdx.x;
        int v = (i < n) ? degi[i] : 0;
        tmp[threadIdx.x] = v;
        __syncthreads();
        for (int s = 1; s < 1024; s <<= 1) {
            int t = (threadIdx.x >= s) ? tmp[threadIdx.x - s] : 0;
            __syncthreads();
            tmp[threadIdx.x] += t;
            __syncthreads();
        }
        if (i < n) off[i] = carry + tmp[threadIdx.x] - v;   // exclusive
        __syncthreads();
        if (threadIdx.x == 1023) carry += tmp[1023];
        __syncthreads();
    }
    if (threadIdx.x == 0) off[n] = carry;
}

__global__ void copy_int_kernel(const int* __restrict__ a, int* __restrict__ b, int n) {
    int i = blockIdx.x * 256 + threadIdx.x;
    if (i < n) b[i] = a[i];
}

// ---------------- CSR fill: eidx[pos] = src[e], pos = cursor[dst[e]]++
__global__ void fill_kernel(const int* __restrict__ src, const int* __restrict__ dst,
                            int* __restrict__ cursor, int* __restrict__ eidx, int n_edges) {
    int e = blockIdx.x * 256 + threadIdx.x;
    if (e < n_edges) {
        int p = atomicAdd(&cursor[dst[e]], 1);
        eidx[p] = src[e];
    }
}

// ---------------- bf16 MFMA GEMM: C[Mpad,512] = A[Mpad,K] @ BT[512,K]^T, fp32 out
// 128x128 block tile, 4 waves (2x2 of 64x64), BK=64, global_load_lds width 16,
// XOR swizzle on 16B units within each 128B LDS row (kills 16-way bank conflict).
__global__ __launch_bounds__(256) void gemm_mfma(const ushort* __restrict__ A,
                                                 const ushort* __restrict__ BT,
                                                 float* __restrict__ C, int K) {
    __shared__ ushort As[128 * 64];
    __shared__ ushort Bs[128 * 64];
    int tid = threadIdx.x;
    int w = tid >> 6, lane = tid & 63;
    int quad = lane >> 4, r16 = lane & 15;
    int m0 = blockIdx.y * 128, n0 = blockIdx.x * 128;
    int wm = (w >> 1) * 64, wn = (w & 1) * 64;

    floatx4 acc[4][4];
#pragma unroll
    for (int i = 0; i < 4; ++i)
#pragma unroll
        for (int j = 0; j < 4; ++j) acc[i][j] = (floatx4){0.f, 0.f, 0.f, 0.f};

    for (int k0 = 0; k0 < K; k0 += 64) {
#pragma unroll
        for (int rr = 0; rr < 4; ++rr) {
            int idx = rr * 256 + tid;            // 16B slot index, 1024 slots per matrix
            int row = idx >> 3, u = idx & 7;
            int gu = u ^ (row & 7);              // swizzle: slot u holds global unit u^(row&7)
            const ushort* ga = A + (size_t)(m0 + row) * K + k0 + gu * 8;
            const ushort* gb = BT + (size_t)(n0 + row) * K + k0 + gu * 8;
            ushort* la = As + (size_t)(rr * 256 + w * 64) * 8;   // wave-uniform LDS base
            ushort* lb = Bs + (size_t)(rr * 256 + w * 64) * 8;
            __builtin_amdgcn_global_load_lds((gp_t)(const void*)ga, (lp_t)(void*)la, 16, 0, 0);
            __builtin_amdgcn_global_load_lds((gp_t)(const void*)gb, (lp_t)(void*)lb, 16, 0, 0);
        }
        __syncthreads();
#pragma unroll
        for (int s = 0; s < 2; ++s) {
            bf16x8 a[4], b[4];
#pragma unroll
            for (int i = 0; i < 4; ++i) {
                int row = wm + i * 16 + r16;
                int au = (s * 4 + quad) ^ (row & 7);
                a[i] = *(const bf16x8*)(As + row * 64 + au * 8);
            }
#pragma unroll
            for (int j = 0; j < 4; ++j) {
                int row = wn + j * 16 + r16;
                int bu = (s * 4 + quad) ^ (row & 7);
                b[j] = *(const bf16x8*)(Bs + row * 64 + bu * 8);
            }
#pragma unroll
            for (int i = 0; i < 4; ++i)
#pragma unroll
                for (int j = 0; j < 4; ++j)
                    acc[i][j] = __builtin_amdgcn_mfma_f32_16x16x32_bf16(a[i], b[j], acc[i][j], 0, 0, 0);
        }
        __syncthreads();
    }
    // epilogue: C/D layout col=lane&15, row=quad*4+reg
#pragma unroll
    for (int i = 0; i < 4; ++i)
#pragma unroll
        for (int j = 0; j < 4; ++j) {
            int col = n0 + wn + j * 16 + r16;
#pragma unroll
            for (int rg = 0; rg < 4; ++rg) {
                int row = m0 + wm + i * 16 + quad * 4 + rg;
                C[(size_t)row * NCOL + col] = acc[i][j][rg];
            }
        }
}

// ---------------- fused gather + combine: one 64-lane wave per node, bf16 out
__global__ __launch_bounds__(256) void gather_kernel(const float* __restrict__ Y,
                                                     const int* __restrict__ off,
                                                     const int* __restrict__ eidx,
                                                     const float* __restrict__ bias,
                                                     ushort* __restrict__ h, int n_nodes) {
    int tid = threadIdx.x;
    int v = blockIdx.x * 4 + (tid >> 6);
    if (v >= n_nodes) return;
    int q4 = (tid & 63) << 2;
    int e0 = off[v], e1 = off[v + 1];
    float4 acc = make_float4(0.f, 0.f, 0.f, 0.f);
    for (int e = e0; e < e1; ++e) {
        int s = eidx[e];
        float4 y = *(const float4*)(Y + (size_t)s * NCOL + q4);
        acc.x += y.x; acc.y += y.y; acc.z += y.z; acc.w += y.w;
    }
    float invd = 1.0f / fmaxf((float)(e1 - e0), 1.0f);
    float4 s = *(const float4*)(Y + (size_t)v * NCOL + HID + q4);
    float4 b = *(const float4*)(bias + q4);
    ushort4 r;
    r.x = f2bf(fmaxf(acc.x * invd + s.x + b.x, 0.f));
    r.y = f2bf(fmaxf(acc.y * invd + s.y + b.y, 0.f));
    r.z = f2bf(fmaxf(acc.z * invd + s.z + b.z, 0.f));
    r.w = f2bf(fmaxf(acc.w * invd + s.w + b.w, 0.f));
    *(ushort4*)(h + (size_t)v * HID + q4) = r;
}

// ---------------- segmented mean-pool (batch sorted), bf16 in, fp32 accumulate
__global__ void pool_kernel(const ushort* __restrict__ h, const int* __restrict__ batch,
                            float* __restrict__ pooled, float* __restrict__ cnt, int n_nodes) {
    int f = threadIdx.x;                     // 256 features
    int v0 = blockIdx.x * 64;
    int vend = min(v0 + 64, n_nodes);
    if (v0 >= n_nodes) return;
    int cur = batch[v0];
    float acc = 0.f, ac = 0.f;
    for (int v = v0; v < vend; ++v) {
        int g = batch[v];
        if (g != cur) {
            atomicAdd(&pooled[cur * HID + f], acc);
            if (f == 0) atomicAdd(&cnt[cur], ac);
            acc = 0.f; ac = 0.f; cur = g;
        }
        acc += bf2f(h[(size_t)v * HID + f]);
        ac += 1.0f;
    }
    atomicAdd(&pooled[cur * HID + f], acc);
    if (f == 0) atomicAdd(&cnt[cur], ac);
}

// ---------------- MLP head: out[g] = relu(pooled_mean @ fc1w + fc1b) @ fc2w + fc2b
__global__ void head_kernel(const float* __restrict__ pooled, const float* __restrict__ cnt,
                            const float* __restrict__ fc1w, const float* __restrict__ fc1b,
                            const float* __restrict__ fc2w, const float* __restrict__ fc2b,
                            float* __restrict__ out) {
    int g = blockIdx.x, j = threadIdx.x;     // 128 threads
    __shared__ float p[256];
    __shared__ float hid[128];
    float inv = 1.0f / fmaxf(cnt[g], 1.0f);
    p[j] = pooled[g * HID + j] * inv;
    p[j + 128] = pooled[g * HID + 128 + j] * inv;
    __syncthreads();
    float a = fc1b[j];
    for (int f = 0; f < 256; ++f) a += p[f] * fc1w[f * 128 + j];
    hid[j] = fmaxf(a, 0.f);
    __syncthreads();
    if (j < 2) {
        float o = fc2b[j];
        for (int t = 0; t < 128; ++t) o += hid[t] * fc2w[t * 2 + j];
        out[g * 2 + j] = o;
    }
}

extern "C" void kernel_launch(void* const* d_in, const int* in_sizes, int n_in,
                              void* d_out, int out_size, void* d_ws, size_t ws_size,
                              hipStream_t stream) {
    const float* x    = (const float*)d_in[0];
    const int*   ei   = (const int*)d_in[1];
    const int*   batch= (const int*)d_in[2];
    const float* W1n  = (const float*)d_in[3];
    const float* W1s  = (const float*)d_in[4];
    const float* b1   = (const float*)d_in[5];
    const float* W2n  = (const float*)d_in[6];
    const float* W2s  = (const float*)d_in[7];
    const float* b2   = (const float*)d_in[8];
    const float* fc1w = (const float*)d_in[9];
    const float* fc1b = (const float*)d_in[10];
    const float* fc2w = (const float*)d_in[11];
    const float* fc2b = (const float*)d_in[12];
    float* out = (float*)d_out;

    const int n_nodes = in_sizes[2];
    const int n_edges = in_sizes[1] / 2;
    const int in_dim  = in_sizes[0] / n_nodes;   // 512
    const int Mpad    = (n_nodes + 127) & ~127;  // 20096
    const int* src = ei;
    const int* dst = ei + n_edges;

    // workspace layout, 256B-aligned slices
    char* wsb = (char*)d_ws;
    size_t cur = 0;
    auto alloc = [&](size_t nbytes) { size_t o = cur; cur = (cur + nbytes + 255) & ~(size_t)255; return o; };
    size_t o_degi = alloc((size_t)n_nodes * 4);
    size_t o_off  = alloc((size_t)(n_nodes + 1) * 4);
    size_t o_cur  = alloc((size_t)n_nodes * 4);
    size_t o_eidx = alloc((size_t)n_edges * 4);
    size_t o_w1   = alloc((size_t)NCOL * in_dim * 2);    // W1catT bf16 [512][512]
    size_t o_w2   = alloc((size_t)NCOL * HID * 2);       // W2catT bf16 [512][256]
    size_t o_xb   = alloc((size_t)Mpad * in_dim * 2);    // x bf16, padded rows
    size_t o_hb   = alloc((size_t)Mpad * HID * 2);       // h bf16, padded rows
    size_t o_y    = alloc((size_t)Mpad * NCOL * 4);      // Y fp32, padded rows
    size_t o_pool = alloc((size_t)16 * HID * 4 + 16 * 4);
    (void)ws_size;

    int*    degi   = (int*)(wsb + o_degi);
    int*    off    = (int*)(wsb + o_off);
    int*    cursor = (int*)(wsb + o_cur);
    int*    eidx   = (int*)(wsb + o_eidx);
    ushort* w1t    = (ushort*)(wsb + o_w1);
    ushort* w2t    = (ushort*)(wsb + o_w2);
    ushort* xb     = (ushort*)(wsb + o_xb);
    ushort* hb     = (ushort*)(wsb + o_hb);
    float*  Y      = (float*)(wsb + o_y);
    float*  pooled = (float*)(wsb + o_pool);
    float*  cnt    = pooled + 16 * HID;

    hipMemsetAsync(degi, 0, (size_t)n_nodes * 4, stream);
    hipMemsetAsync(pooled, 0, (size_t)(16 * HID + 16) * 4, stream);

    // ---- CSR build (by dst)
    degi_kernel<<<(n_edges + 255) / 256, 256, 0, stream>>>(dst, degi, n_edges);
    scan_kernel<<<1, 1024, 0, stream>>>(degi, off, n_nodes);
    copy_int_kernel<<<(n_nodes + 255) / 256, 256, 0, stream>>>(off, cursor, n_nodes);
    fill_kernel<<<(n_edges + 255) / 256, 256, 0, stream>>>(src, dst, cursor, eidx, n_edges);

    // ---- convert x to bf16; pack+transpose weights to bf16 B^T
    int n4 = n_nodes * in_dim / 4;
    cvt_kernel<<<(n4 + 255) / 256, 256, 0, stream>>>(x, xb, n4);
    packT_kernel<<<(NCOL * in_dim + 255) / 256, 256, 0, stream>>>(W1n, W1s, w1t, in_dim);
    packT_kernel<<<(NCOL * HID + 255) / 256, 256, 0, stream>>>(W2n, W2s, w2t, HID);

    dim3 gemm_grid(NCOL / 128, Mpad / 128);
    int gather_blocks = (n_nodes + 3) / 4;

    // ---- layer 1
    gemm_mfma<<<gemm_grid, 256, 0, stream>>>(xb, w1t, Y, in_dim);
    gather_kernel<<<gather_blocks, 256, 0, stream>>>(Y, off, eidx, b1, hb, n_nodes);

    // ---- layer 2
    gemm_mfma<<<gemm_grid, 256, 0, stream>>>(hb, w2t, Y, HID);
    gather_kernel<<<gather_blocks, 256, 0, stream>>>(Y, off, eidx, b2, hb, n_nodes);

    // ---- pool + head
    pool_kernel<<<(n_nodes + 63) / 64, 256, 0, stream>>>(hb, batch, pooled, cnt, n_nodes);
    head_kernel<<<16, 128, 0, stream>>>(pooled, cnt, fc1w, fc1b, fc2w, fc2b, out);
}

// Round 4
// 306.451 us; speedup vs baseline: 4.8392x; 1.0198x over previous
//
#include <hip/hip_runtime.h>
#include <hip/hip_bf16.h>

// GraphSAGE forward. R3: bf16 neighbor payload (Yn bf16 / Ys fp32 split epilogue),
// wave-shuffle CSR scan (no barriers), fused cursor copy.
// Per layer: [Yn|Ys] = H_in @ [Wn | Ws], then fused gather:
//   h_out[v] = bf16( relu( (sum_e bf2f(Yn[eidx[e]])) / max(deg,1) + Ys[v] + b ) )

#define HID 256
#define NCOL 512

typedef __bf16 bf16x8 __attribute__((ext_vector_type(8)));
typedef float floatx4 __attribute__((ext_vector_type(4)));
typedef unsigned int u32;
typedef const u32 __attribute__((address_space(1)))* gp_t;
typedef u32 __attribute__((address_space(3)))* lp_t;

__device__ __forceinline__ ushort f2bf(float f) {   // round-to-nearest-even
    unsigned u = __float_as_uint(f);
    u += 0x7fffu + ((u >> 16) & 1u);
    return (ushort)(u >> 16);
}
__device__ __forceinline__ float bf2f(ushort b) {
    return __uint_as_float(((unsigned)b) << 16);
}

// ---------------- f32 -> bf16 bulk convert (n4 = n/4)
__global__ void cvt_kernel(const float* __restrict__ in, ushort* __restrict__ out, int n4) {
    int i = blockIdx.x * 256 + threadIdx.x;
    if (i >= n4) return;
    float4 v = ((const float4*)in)[i];
    ushort4 o;
    o.x = f2bf(v.x); o.y = f2bf(v.y); o.z = f2bf(v.z); o.w = f2bf(v.w);
    ((ushort4*)out)[i] = o;
}

// ---------------- weight pack+transpose: WT[n][k] bf16, n<256 -> Wn[k][n], else Ws[k][n-256]
__global__ void packT_kernel(const float* __restrict__ Wn, const float* __restrict__ Ws,
                             ushort* __restrict__ WT, int K) {
    int gid = blockIdx.x * 256 + threadIdx.x;
    if (gid >= NCOL * K) return;
    int n = gid / K, k = gid - n * K;
    float v = (n < HID) ? Wn[k * HID + n] : Ws[k * HID + (n - HID)];
    WT[gid] = f2bf(v);
}

// ---------------- int degree histogram (by dst)
__global__ void degi_kernel(const int* __restrict__ dst, int* __restrict__ degi, int n_edges) {
    int e = blockIdx.x * 256 + threadIdx.x;
    if (e < n_edges) atomicAdd(&degi[dst[e]], 1);
}

// ---------------- single-wave shuffle scan: off (exclusive, off[n]=total) + cursor copy
__global__ __launch_bounds__(64) void scan_kernel(const int* __restrict__ degi,
                                                  int* __restrict__ off,
                                                  int* __restrict__ cursor, int n) {
    int lane = threadIdx.x;   // 64
    int carry = 0;
    for (int base = 0; base < n; base += 256) {
        int i0 = base + lane * 4;
        int v0 = (i0 + 0 < n) ? degi[i0 + 0] : 0;
        int v1 = (i0 + 1 < n) ? degi[i0 + 1] : 0;
        int v2 = (i0 + 2 < n) ? degi[i0 + 2] : 0;
        int v3 = (i0 + 3 < n) ? degi[i0 + 3] : 0;
        int local = v0 + v1 + v2 + v3;
        int s = local;
#pragma unroll
        for (int d = 1; d < 64; d <<= 1) {
            int t = __shfl_up(s, d, 64);
            if (lane >= d) s += t;
        }
        int excl = carry + s - local;
        if (i0 + 0 < n) { off[i0 + 0] = excl; cursor[i0 + 0] = excl; }
        excl += v0;
        if (i0 + 1 < n) { off[i0 + 1] = excl; cursor[i0 + 1] = excl; }
        excl += v1;
        if (i0 + 2 < n) { off[i0 + 2] = excl; cursor[i0 + 2] = excl; }
        excl += v2;
        if (i0 + 3 < n) { off[i0 + 3] = excl; cursor[i0 + 3] = excl; }
        carry += __shfl(s, 63, 64);
    }
    if (lane == 0) off[n] = carry;
}

// ---------------- CSR fill: eidx[pos] = src[e], pos = cursor[dst[e]]++
__global__ void fill_kernel(const int* __restrict__ src, const int* __restrict__ dst,
                            int* __restrict__ cursor, int* __restrict__ eidx, int n_edges) {
    int e = blockIdx.x * 256 + threadIdx.x;
    if (e < n_edges) {
        int p = atomicAdd(&cursor[dst[e]], 1);
        eidx[p] = src[e];
    }
}

// ---------------- bf16 MFMA GEMM: [Yn|Ys] = A[Mpad,K] @ BT[512,K]^T
// 128x128 block tile, 4 waves (2x2 of 64x64), BK=64, global_load_lds width 16,
// XOR swizzle on 16B units within each 128B LDS row.
// Epilogue: cols 0..255 -> Ynb (bf16), cols 256..511 -> Ys (fp32). Wave-uniform split.
__global__ __launch_bounds__(256) void gemm_mfma(const ushort* __restrict__ A,
                                                 const ushort* __restrict__ BT,
                                                 ushort* __restrict__ Ynb,
                                                 float* __restrict__ Ys, int K) {
    __shared__ ushort As[128 * 64];
    __shared__ ushort Bs[128 * 64];
    int tid = threadIdx.x;
    int w = tid >> 6, lane = tid & 63;
    int quad = lane >> 4, r16 = lane & 15;
    int m0 = blockIdx.y * 128, n0 = blockIdx.x * 128;
    int wm = (w >> 1) * 64, wn = (w & 1) * 64;

    floatx4 acc[4][4];
#pragma unroll
    for (int i = 0; i < 4; ++i)
#pragma unroll
        for (int j = 0; j < 4; ++j) acc[i][j] = (floatx4){0.f, 0.f, 0.f, 0.f};

    for (int k0 = 0; k0 < K; k0 += 64) {
#pragma unroll
        for (int rr = 0; rr < 4; ++rr) {
            int idx = rr * 256 + tid;            // 16B slot index
            int row = idx >> 3, u = idx & 7;
            int gu = u ^ (row & 7);              // swizzle
            const ushort* ga = A + (size_t)(m0 + row) * K + k0 + gu * 8;
            const ushort* gb = BT + (size_t)(n0 + row) * K + k0 + gu * 8;
            ushort* la = As + (size_t)(rr * 256 + w * 64) * 8;   // wave-uniform base
            ushort* lb = Bs + (size_t)(rr * 256 + w * 64) * 8;
            __builtin_amdgcn_global_load_lds((gp_t)(const void*)ga, (lp_t)(void*)la, 16, 0, 0);
            __builtin_amdgcn_global_load_lds((gp_t)(const void*)gb, (lp_t)(void*)lb, 16, 0, 0);
        }
        __syncthreads();
#pragma unroll
        for (int s = 0; s < 2; ++s) {
            bf16x8 a[4], b[4];
#pragma unroll
            for (int i = 0; i < 4; ++i) {
                int row = wm + i * 16 + r16;
                int au = (s * 4 + quad) ^ (row & 7);
                a[i] = *(const bf16x8*)(As + row * 64 + au * 8);
            }
#pragma unroll
            for (int j = 0; j < 4; ++j) {
                int row = wn + j * 16 + r16;
                int bu = (s * 4 + quad) ^ (row & 7);
                b[j] = *(const bf16x8*)(Bs + row * 64 + bu * 8);
            }
#pragma unroll
            for (int i = 0; i < 4; ++i)
#pragma unroll
                for (int j = 0; j < 4; ++j)
                    acc[i][j] = __builtin_amdgcn_mfma_f32_16x16x32_bf16(a[i], b[j], acc[i][j], 0, 0, 0);
        }
        __syncthreads();
    }
    // epilogue: C/D layout col=lane&15, row=quad*4+reg; wave-tile is entirely Yn or Ys
    bool isYn = (n0 + wn) < HID;
#pragma unroll
    for (int i = 0; i < 4; ++i)
#pragma unroll
        for (int j = 0; j < 4; ++j) {
            int col16 = n0 + wn + j * 16 + r16;
#pragma unroll
            for (int rg = 0; rg < 4; ++rg) {
                int row = m0 + wm + i * 16 + quad * 4 + rg;
                if (isYn) Ynb[(size_t)row * HID + col16] = f2bf(acc[i][j][rg]);
                else      Ys[(size_t)row * HID + (col16 - HID)] = acc[i][j][rg];
            }
        }
}

// ---------------- fused gather + combine: one 64-lane wave per node, bf16 in/out
__global__ __launch_bounds__(256) void gather_kernel(const ushort* __restrict__ Ynb,
                                                     const float* __restrict__ Ys,
                                                     const int* __restrict__ off,
                                                     const int* __restrict__ eidx,
                                                     const float* __restrict__ bias,
                                                     ushort* __restrict__ h, int n_nodes) {
    int tid = threadIdx.x;
    int v = blockIdx.x * 4 + (tid >> 6);
    if (v >= n_nodes) return;
    int q4 = (tid & 63) << 2;
    int e0 = off[v], e1 = off[v + 1];
    float4 acc = make_float4(0.f, 0.f, 0.f, 0.f);
    for (int e = e0; e < e1; ++e) {
        int s = eidx[e];
        ushort4 y = *(const ushort4*)(Ynb + (size_t)s * HID + q4);
        acc.x += bf2f(y.x); acc.y += bf2f(y.y);
        acc.z += bf2f(y.z); acc.w += bf2f(y.w);
    }
    float invd = 1.0f / fmaxf((float)(e1 - e0), 1.0f);
    float4 s = *(const float4*)(Ys + (size_t)v * HID + q4);
    float4 b = *(const float4*)(bias + q4);
    ushort4 r;
    r.x = f2bf(fmaxf(acc.x * invd + s.x + b.x, 0.f));
    r.y = f2bf(fmaxf(acc.y * invd + s.y + b.y, 0.f));
    r.z = f2bf(fmaxf(acc.z * invd + s.z + b.z, 0.f));
    r.w = f2bf(fmaxf(acc.w * invd + s.w + b.w, 0.f));
    *(ushort4*)(h + (size_t)v * HID + q4) = r;
}

// ---------------- segmented mean-pool (batch sorted), bf16 in, fp32 accumulate
__global__ void pool_kernel(const ushort* __restrict__ h, const int* __restrict__ batch,
                            float* __restrict__ pooled, float* __restrict__ cnt, int n_nodes) {
    int f = threadIdx.x;                     // 256 features
    int v0 = blockIdx.x * 64;
    int vend = min(v0 + 64, n_nodes);
    if (v0 >= n_nodes) return;
    int cur = batch[v0];
    float acc = 0.f, ac = 0.f;
    for (int v = v0; v < vend; ++v) {
        int g = batch[v];
        if (g != cur) {
            atomicAdd(&pooled[cur * HID + f], acc);
            if (f == 0) atomicAdd(&cnt[cur], ac);
            acc = 0.f; ac = 0.f; cur = g;
        }
        acc += bf2f(h[(size_t)v * HID + f]);
        ac += 1.0f;
    }
    atomicAdd(&pooled[cur * HID + f], acc);
    if (f == 0) atomicAdd(&cnt[cur], ac);
}

// ---------------- MLP head: out[g] = relu(pooled_mean @ fc1w + fc1b) @ fc2w + fc2b
__global__ void head_kernel(const float* __restrict__ pooled, const float* __restrict__ cnt,
                            const float* __restrict__ fc1w, const float* __restrict__ fc1b,
                            const float* __restrict__ fc2w, const float* __restrict__ fc2b,
                            float* __restrict__ out) {
    int g = blockIdx.x, j = threadIdx.x;     // 128 threads
    __shared__ float p[256];
    __shared__ float hid[128];
    float inv = 1.0f / fmaxf(cnt[g], 1.0f);
    p[j] = pooled[g * HID + j] * inv;
    p[j + 128] = pooled[g * HID + 128 + j] * inv;
    __syncthreads();
    float a = fc1b[j];
    for (int f = 0; f < 256; ++f) a += p[f] * fc1w[f * 128 + j];
    hid[j] = fmaxf(a, 0.f);
    __syncthreads();
    if (j < 2) {
        float o = fc2b[j];
        for (int t = 0; t < 128; ++t) o += hid[t] * fc2w[t * 2 + j];
        out[g * 2 + j] = o;
    }
}

extern "C" void kernel_launch(void* const* d_in, const int* in_sizes, int n_in,
                              void* d_out, int out_size, void* d_ws, size_t ws_size,
                              hipStream_t stream) {
    const float* x    = (const float*)d_in[0];
    const int*   ei   = (const int*)d_in[1];
    const int*   batch= (const int*)d_in[2];
    const float* W1n  = (const float*)d_in[3];
    const float* W1s  = (const float*)d_in[4];
    const float* b1   = (const float*)d_in[5];
    const float* W2n  = (const float*)d_in[6];
    const float* W2s  = (const float*)d_in[7];
    const float* b2   = (const float*)d_in[8];
    const float* fc1w = (const float*)d_in[9];
    const float* fc1b = (const float*)d_in[10];
    const float* fc2w = (const float*)d_in[11];
    const float* fc2b = (const float*)d_in[12];
    float* out = (float*)d_out;

    const int n_nodes = in_sizes[2];
    const int n_edges = in_sizes[1] / 2;
    const int in_dim  = in_sizes[0] / n_nodes;   // 512
    const int Mpad    = (n_nodes + 127) & ~127;  // 20096
    const int* src = ei;
    const int* dst = ei + n_edges;

    // workspace layout, 256B-aligned slices
    char* wsb = (char*)d_ws;
    size_t cur = 0;
    auto alloc = [&](size_t nbytes) { size_t o = cur; cur = (cur + nbytes + 255) & ~(size_t)255; return o; };
    size_t o_degi = alloc((size_t)n_nodes * 4);
    size_t o_off  = alloc((size_t)(n_nodes + 1) * 4);
    size_t o_cur  = alloc((size_t)n_nodes * 4);
    size_t o_eidx = alloc((size_t)n_edges * 4);
    size_t o_w1   = alloc((size_t)NCOL * in_dim * 2);    // W1catT bf16 [512][512]
    size_t o_w2   = alloc((size_t)NCOL * HID * 2);       // W2catT bf16 [512][256]
    size_t o_xb   = alloc((size_t)Mpad * in_dim * 2);    // x bf16, padded rows
    size_t o_hb   = alloc((size_t)Mpad * HID * 2);       // h bf16, padded rows
    size_t o_ynb  = alloc((size_t)Mpad * HID * 2);       // Yn bf16
    size_t o_ys   = alloc((size_t)Mpad * HID * 4);       // Ys fp32
    size_t o_pool = alloc((size_t)16 * HID * 4 + 16 * 4);
    (void)ws_size;

    int*    degi   = (int*)(wsb + o_degi);
    int*    off    = (int*)(wsb + o_off);
    int*    cursor = (int*)(wsb + o_cur);
    int*    eidx   = (int*)(wsb + o_eidx);
    ushort* w1t    = (ushort*)(wsb + o_w1);
    ushort* w2t    = (ushort*)(wsb + o_w2);
    ushort* xb     = (ushort*)(wsb + o_xb);
    ushort* hb     = (ushort*)(wsb + o_hb);
    ushort* Ynb    = (ushort*)(wsb + o_ynb);
    float*  Ys     = (float*)(wsb + o_ys);
    float*  pooled = (float*)(wsb + o_pool);
    float*  cnt    = pooled + 16 * HID;

    hipMemsetAsync(degi, 0, (size_t)n_nodes * 4, stream);
    hipMemsetAsync(pooled, 0, (size_t)(16 * HID + 16) * 4, stream);

    // ---- CSR build (by dst)
    degi_kernel<<<(n_edges + 255) / 256, 256, 0, stream>>>(dst, degi, n_edges);
    scan_kernel<<<1, 64, 0, stream>>>(degi, off, cursor, n_nodes);
    fill_kernel<<<(n_edges + 255) / 256, 256, 0, stream>>>(src, dst, cursor, eidx, n_edges);

    // ---- convert x to bf16; pack+transpose weights to bf16 B^T
    int n4 = n_nodes * in_dim / 4;
    cvt_kernel<<<(n4 + 255) / 256, 256, 0, stream>>>(x, xb, n4);
    packT_kernel<<<(NCOL * in_dim + 255) / 256, 256, 0, stream>>>(W1n, W1s, w1t, in_dim);
    packT_kernel<<<(NCOL * HID + 255) / 256, 256, 0, stream>>>(W2n, W2s, w2t, HID);

    dim3 gemm_grid(NCOL / 128, Mpad / 128);
    int gather_blocks = (n_nodes + 3) / 4;

    // ---- layer 1
    gemm_mfma<<<gemm_grid, 256, 0, stream>>>(xb, w1t, Ynb, Ys, in_dim);
    gather_kernel<<<gather_blocks, 256, 0, stream>>>(Ynb, Ys, off, eidx, b1, hb, n_nodes);

    // ---- layer 2
    gemm_mfma<<<gemm_grid, 256, 0, stream>>>(hb, w2t, Ynb, Ys, HID);
    gather_kernel<<<gather_blocks, 256, 0, stream>>>(Ynb, Ys, off, eidx, b2, hb, n_nodes);

    // ---- pool + head
    pool_kernel<<<(n_nodes + 63) / 64, 256, 0, stream>>>(hb, batch, pooled, cnt, n_nodes);
    head_kernel<<<16, 128, 0, stream>>>(pooled, cnt, fc1w, fc1b, fc2w, fc2b, out);
}

// Round 5
// 251.874 us; speedup vs baseline: 5.8878x; 1.2167x over previous
//
#include <hip/hip_runtime.h>
#include <hip/hip_bf16.h>

// GraphSAGE forward. R4: hierarchical CSR scan (3 parallel kernels), double-buffered
// GEMM staging (prefetch overlaps compute), gather edge-loop unroll-2.
// Per layer: [Yn|Ys] = H_in @ [Wn | Ws], then fused gather:
//   h_out[v] = bf16( relu( (sum_e bf2f(Yn[eidx[e]])) / max(deg,1) + Ys[v] + b ) )

#define HID 256
#define NCOL 512

typedef __bf16 bf16x8 __attribute__((ext_vector_type(8)));
typedef float floatx4 __attribute__((ext_vector_type(4)));
typedef unsigned int u32;
typedef const u32 __attribute__((address_space(1)))* gp_t;
typedef u32 __attribute__((address_space(3)))* lp_t;

__device__ __forceinline__ ushort f2bf(float f) {   // round-to-nearest-even
    unsigned u = __float_as_uint(f);
    u += 0x7fffu + ((u >> 16) & 1u);
    return (ushort)(u >> 16);
}
__device__ __forceinline__ float bf2f(ushort b) {
    return __uint_as_float(((unsigned)b) << 16);
}

// ---------------- f32 -> bf16 bulk convert (n4 = n/4)
__global__ void cvt_kernel(const float* __restrict__ in, ushort* __restrict__ out, int n4) {
    int i = blockIdx.x * 256 + threadIdx.x;
    if (i >= n4) return;
    float4 v = ((const float4*)in)[i];
    ushort4 o;
    o.x = f2bf(v.x); o.y = f2bf(v.y); o.z = f2bf(v.z); o.w = f2bf(v.w);
    ((ushort4*)out)[i] = o;
}

// ---------------- weight pack+transpose: WT[n][k] bf16, n<256 -> Wn[k][n], else Ws[k][n-256]
__global__ void packT_kernel(const float* __restrict__ Wn, const float* __restrict__ Ws,
                             ushort* __restrict__ WT, int K) {
    int gid = blockIdx.x * 256 + threadIdx.x;
    if (gid >= NCOL * K) return;
    int n = gid / K, k = gid - n * K;
    float v = (n < HID) ? Wn[k * HID + n] : Ws[k * HID + (n - HID)];
    WT[gid] = f2bf(v);
}

// ---------------- int degree histogram (by dst)
__global__ void degi_kernel(const int* __restrict__ dst, int* __restrict__ degi, int n_edges) {
    int e = blockIdx.x * 256 + threadIdx.x;
    if (e < n_edges) atomicAdd(&degi[dst[e]], 1);
}

// ---------------- scan phase 1: per-256-chunk sums
__global__ __launch_bounds__(256) void psum_kernel(const int* __restrict__ degi,
                                                   int* __restrict__ partials, int n) {
    int t = threadIdx.x;
    int i = blockIdx.x * 256 + t;
    int v = (i < n) ? degi[i] : 0;
#pragma unroll
    for (int d = 1; d < 64; d <<= 1) v += __shfl_xor(v, d, 64);
    __shared__ int wsum[4];
    if ((t & 63) == 0) wsum[t >> 6] = v;
    __syncthreads();
    if (t == 0) partials[blockIdx.x] = wsum[0] + wsum[1] + wsum[2] + wsum[3];
}

// ---------------- scan phase 2: 1-wave exclusive scan of partials (in place), total -> off[n]
__global__ __launch_bounds__(64) void pscan_kernel(int* __restrict__ partials,
                                                   int* __restrict__ off, int nb, int n) {
    int lane = threadIdx.x;
    int carry = 0;
    for (int base = 0; base < nb; base += 256) {
        int i0 = base + lane * 4;
        int v0 = (i0 + 0 < nb) ? partials[i0 + 0] : 0;
        int v1 = (i0 + 1 < nb) ? partials[i0 + 1] : 0;
        int v2 = (i0 + 2 < nb) ? partials[i0 + 2] : 0;
        int v3 = (i0 + 3 < nb) ? partials[i0 + 3] : 0;
        int local = v0 + v1 + v2 + v3;
        int s = local;
#pragma unroll
        for (int d = 1; d < 64; d <<= 1) {
            int t = __shfl_up(s, d, 64);
            if (lane >= d) s += t;
        }
        int excl = carry + s - local;
        if (i0 + 0 < nb) partials[i0 + 0] = excl;
        excl += v0;
        if (i0 + 1 < nb) partials[i0 + 1] = excl;
        excl += v1;
        if (i0 + 2 < nb) partials[i0 + 2] = excl;
        excl += v2;
        if (i0 + 3 < nb) partials[i0 + 3] = excl;
        carry += __shfl(s, 63, 64);
    }
    if (lane == 0) off[n] = carry;
}

// ---------------- scan phase 3: per-chunk rescan + chunk offset -> off, cursor
__global__ __launch_bounds__(256) void scan2_kernel(const int* __restrict__ degi,
                                                    const int* __restrict__ partials,
                                                    int* __restrict__ off,
                                                    int* __restrict__ cursor, int n) {
    int t = threadIdx.x, lane = t & 63, w = t >> 6;
    int i = blockIdx.x * 256 + t;
    int v = (i < n) ? degi[i] : 0;
    int s = v;
#pragma unroll
    for (int d = 1; d < 64; d <<= 1) {
        int u = __shfl_up(s, d, 64);
        if (lane >= d) s += u;
    }
    __shared__ int wsum[4];
    if (lane == 63) wsum[w] = s;
    __syncthreads();
    int woff = 0;
    for (int k = 0; k < w; ++k) woff += wsum[k];
    int excl = partials[blockIdx.x] + woff + s - v;
    if (i < n) { off[i] = excl; cursor[i] = excl; }
}

// ---------------- CSR fill: eidx[pos] = src[e], pos = cursor[dst[e]]++
__global__ void fill_kernel(const int* __restrict__ src, const int* __restrict__ dst,
                            int* __restrict__ cursor, int* __restrict__ eidx, int n_edges) {
    int e = blockIdx.x * 256 + threadIdx.x;
    if (e < n_edges) {
        int p = atomicAdd(&cursor[dst[e]], 1);
        eidx[p] = src[e];
    }
}

// ---------------- bf16 MFMA GEMM: [Yn|Ys] = A[Mpad,K] @ BT[512,K]^T
// 128x128 tile, 4 waves (2x2 of 64x64), BK=64, double-buffered global_load_lds
// (prefetch next tile after barrier, compute current -> loads overlap compute),
// XOR swizzle on 16B units within each 128B LDS row.
// Epilogue: cols 0..255 -> Ynb (bf16), cols 256..511 -> Ys (fp32).
__global__ __launch_bounds__(256) void gemm_mfma(const ushort* __restrict__ A,
                                                 const ushort* __restrict__ BT,
                                                 ushort* __restrict__ Ynb,
                                                 float* __restrict__ Ys, int K) {
    __shared__ ushort As[2][128 * 64];
    __shared__ ushort Bs[2][128 * 64];
    int tid = threadIdx.x;
    int w = tid >> 6, lane = tid & 63;
    int quad = lane >> 4, r16 = lane & 15;
    int m0 = blockIdx.y * 128, n0 = blockIdx.x * 128;
    int wm = (w >> 1) * 64, wn = (w & 1) * 64;

    // staging addressing (same every tile): 16B slot idx = rr*256+tid
    int srow[4], sgu[4];
#pragma unroll
    for (int rr = 0; rr < 4; ++rr) {
        int idx = rr * 256 + tid;
        srow[rr] = idx >> 3;
        sgu[rr] = (idx & 7) ^ (srow[rr] & 7);
    }

    auto stage = [&](int buf, int k0) {
#pragma unroll
        for (int rr = 0; rr < 4; ++rr) {
            const ushort* ga = A + (size_t)(m0 + srow[rr]) * K + k0 + sgu[rr] * 8;
            const ushort* gb = BT + (size_t)(n0 + srow[rr]) * K + k0 + sgu[rr] * 8;
            ushort* la = As[buf] + (size_t)(rr * 256 + w * 64) * 8;   // wave-uniform base
            ushort* lb = Bs[buf] + (size_t)(rr * 256 + w * 64) * 8;
            __builtin_amdgcn_global_load_lds((gp_t)(const void*)ga, (lp_t)(void*)la, 16, 0, 0);
            __builtin_amdgcn_global_load_lds((gp_t)(const void*)gb, (lp_t)(void*)lb, 16, 0, 0);
        }
    };

    floatx4 acc[4][4];
#pragma unroll
    for (int i = 0; i < 4; ++i)
#pragma unroll
        for (int j = 0; j < 4; ++j) acc[i][j] = (floatx4){0.f, 0.f, 0.f, 0.f};

    const int nk = K >> 6;
    stage(0, 0);
    for (int t = 0; t < nk; ++t) {
        int cb = t & 1;
        __syncthreads();                      // drains prefetch into buf cb
        if (t + 1 < nk) stage(cb ^ 1, (t + 1) << 6);   // overlap with compute below
        const ushort* Ab = As[cb];
        const ushort* Bb = Bs[cb];
#pragma unroll
        for (int s = 0; s < 2; ++s) {
            bf16x8 a[4], b[4];
#pragma unroll
            for (int i = 0; i < 4; ++i) {
                int row = wm + i * 16 + r16;
                int au = (s * 4 + quad) ^ (row & 7);
                a[i] = *(const bf16x8*)(Ab + row * 64 + au * 8);
            }
#pragma unroll
            for (int j = 0; j < 4; ++j) {
                int row = wn + j * 16 + r16;
                int bu = (s * 4 + quad) ^ (row & 7);
                b[j] = *(const bf16x8*)(Bb + row * 64 + bu * 8);
            }
#pragma unroll
            for (int i = 0; i < 4; ++i)
#pragma unroll
                for (int j = 0; j < 4; ++j)
                    acc[i][j] = __builtin_amdgcn_mfma_f32_16x16x32_bf16(a[i], b[j], acc[i][j], 0, 0, 0);
        }
    }
    // epilogue: C/D layout col=lane&15, row=quad*4+reg; wave-tile entirely Yn or Ys
    bool isYn = (n0 + wn) < HID;
#pragma unroll
    for (int i = 0; i < 4; ++i)
#pragma unroll
        for (int j = 0; j < 4; ++j) {
            int col16 = n0 + wn + j * 16 + r16;
#pragma unroll
            for (int rg = 0; rg < 4; ++rg) {
                int row = m0 + wm + i * 16 + quad * 4 + rg;
                if (isYn) Ynb[(size_t)row * HID + col16] = f2bf(acc[i][j][rg]);
                else      Ys[(size_t)row * HID + (col16 - HID)] = acc[i][j][rg];
            }
        }
}

// ---------------- fused gather + combine: one 64-lane wave per node, unroll-2
__global__ __launch_bounds__(256) void gather_kernel(const ushort* __restrict__ Ynb,
                                                     const float* __restrict__ Ys,
                                                     const int* __restrict__ off,
                                                     const int* __restrict__ eidx,
                                                     const float* __restrict__ bias,
                                                     ushort* __restrict__ h, int n_nodes) {
    int tid = threadIdx.x;
    int v = blockIdx.x * 4 + (tid >> 6);
    if (v >= n_nodes) return;
    int q4 = (tid & 63) << 2;
    int e0 = off[v], e1 = off[v + 1];
    float4 acc0 = make_float4(0.f, 0.f, 0.f, 0.f);
    float4 acc1 = make_float4(0.f, 0.f, 0.f, 0.f);
    int e = e0;
    for (; e + 1 < e1; e += 2) {
        int s0 = eidx[e], s1 = eidx[e + 1];
        ushort4 y0 = *(const ushort4*)(Ynb + (size_t)s0 * HID + q4);
        ushort4 y1 = *(const ushort4*)(Ynb + (size_t)s1 * HID + q4);
        acc0.x += bf2f(y0.x); acc0.y += bf2f(y0.y);
        acc0.z += bf2f(y0.z); acc0.w += bf2f(y0.w);
        acc1.x += bf2f(y1.x); acc1.y += bf2f(y1.y);
        acc1.z += bf2f(y1.z); acc1.w += bf2f(y1.w);
    }
    if (e < e1) {
        ushort4 y = *(const ushort4*)(Ynb + (size_t)eidx[e] * HID + q4);
        acc0.x += bf2f(y.x); acc0.y += bf2f(y.y);
        acc0.z += bf2f(y.z); acc0.w += bf2f(y.w);
    }
    float invd = 1.0f / fmaxf((float)(e1 - e0), 1.0f);
    float4 s = *(const float4*)(Ys + (size_t)v * HID + q4);
    float4 b = *(const float4*)(bias + q4);
    ushort4 r;
    r.x = f2bf(fmaxf((acc0.x + acc1.x) * invd + s.x + b.x, 0.f));
    r.y = f2bf(fmaxf((acc0.y + acc1.y) * invd + s.y + b.y, 0.f));
    r.z = f2bf(fmaxf((acc0.z + acc1.z) * invd + s.z + b.z, 0.f));
    r.w = f2bf(fmaxf((acc0.w + acc1.w) * invd + s.w + b.w, 0.f));
    *(ushort4*)(h + (size_t)v * HID + q4) = r;
}

// ---------------- segmented mean-pool (batch sorted), bf16 in, fp32 accumulate
__global__ void pool_kernel(const ushort* __restrict__ h, const int* __restrict__ batch,
                            float* __restrict__ pooled, float* __restrict__ cnt, int n_nodes) {
    int f = threadIdx.x;                     // 256 features
    int v0 = blockIdx.x * 64;
    int vend = min(v0 + 64, n_nodes);
    if (v0 >= n_nodes) return;
    int cur = batch[v0];
    float acc = 0.f, ac = 0.f;
    for (int v = v0; v < vend; ++v) {
        int g = batch[v];
        if (g != cur) {
            atomicAdd(&pooled[cur * HID + f], acc);
            if (f == 0) atomicAdd(&cnt[cur], ac);
            acc = 0.f; ac = 0.f; cur = g;
        }
        acc += bf2f(h[(size_t)v * HID + f]);
        ac += 1.0f;
    }
    atomicAdd(&pooled[cur * HID + f], acc);
    if (f == 0) atomicAdd(&cnt[cur], ac);
}

// ---------------- MLP head: out[g] = relu(pooled_mean @ fc1w + fc1b) @ fc2w + fc2b
__global__ void head_kernel(const float* __restrict__ pooled, const float* __restrict__ cnt,
                            const float* __restrict__ fc1w, const float* __restrict__ fc1b,
                            const float* __restrict__ fc2w, const float* __restrict__ fc2b,
                            float* __restrict__ out) {
    int g = blockIdx.x, j = threadIdx.x;     // 128 threads
    __shared__ float p[256];
    __shared__ float hid[128];
    float inv = 1.0f / fmaxf(cnt[g], 1.0f);
    p[j] = pooled[g * HID + j] * inv;
    p[j + 128] = pooled[g * HID + 128 + j] * inv;
    __syncthreads();
    float a = fc1b[j];
    for (int f = 0; f < 256; ++f) a += p[f] * fc1w[f * 128 + j];
    hid[j] = fmaxf(a, 0.f);
    __syncthreads();
    if (j < 2) {
        float o = fc2b[j];
        for (int t = 0; t < 128; ++t) o += hid[t] * fc2w[t * 2 + j];
        out[g * 2 + j] = o;
    }
}

extern "C" void kernel_launch(void* const* d_in, const int* in_sizes, int n_in,
                              void* d_out, int out_size, void* d_ws, size_t ws_size,
                              hipStream_t stream) {
    const float* x    = (const float*)d_in[0];
    const int*   ei   = (const int*)d_in[1];
    const int*   batch= (const int*)d_in[2];
    const float* W1n  = (const float*)d_in[3];
    const float* W1s  = (const float*)d_in[4];
    const float* b1   = (const float*)d_in[5];
    const float* W2n  = (const float*)d_in[6];
    const float* W2s  = (const float*)d_in[7];
    const float* b2   = (const float*)d_in[8];
    const float* fc1w = (const float*)d_in[9];
    const float* fc1b = (const float*)d_in[10];
    const float* fc2w = (const float*)d_in[11];
    const float* fc2b = (const float*)d_in[12];
    float* out = (float*)d_out;

    const int n_nodes = in_sizes[2];
    const int n_edges = in_sizes[1] / 2;
    const int in_dim  = in_sizes[0] / n_nodes;   // 512
    const int Mpad    = (n_nodes + 127) & ~127;  // 20096
    const int nb      = (n_nodes + 255) / 256;   // scan chunks
    const int* src = ei;
    const int* dst = ei + n_edges;

    // workspace layout, 256B-aligned slices
    char* wsb = (char*)d_ws;
    size_t cur = 0;
    auto alloc = [&](size_t nbytes) { size_t o = cur; cur = (cur + nbytes + 255) & ~(size_t)255; return o; };
    size_t o_degi = alloc((size_t)n_nodes * 4);
    size_t o_off  = alloc((size_t)(n_nodes + 1) * 4);
    size_t o_cur  = alloc((size_t)n_nodes * 4);
    size_t o_part = alloc((size_t)nb * 4);
    size_t o_eidx = alloc((size_t)n_edges * 4);
    size_t o_w1   = alloc((size_t)NCOL * in_dim * 2);    // W1catT bf16 [512][512]
    size_t o_w2   = alloc((size_t)NCOL * HID * 2);       // W2catT bf16 [512][256]
    size_t o_xb   = alloc((size_t)Mpad * in_dim * 2);    // x bf16, padded rows
    size_t o_hb   = alloc((size_t)Mpad * HID * 2);       // h bf16, padded rows
    size_t o_ynb  = alloc((size_t)Mpad * HID * 2);       // Yn bf16
    size_t o_ys   = alloc((size_t)Mpad * HID * 4);       // Ys fp32
    size_t o_pool = alloc((size_t)16 * HID * 4 + 16 * 4);
    (void)ws_size;

    int*    degi    = (int*)(wsb + o_degi);
    int*    off     = (int*)(wsb + o_off);
    int*    cursor  = (int*)(wsb + o_cur);
    int*    partials= (int*)(wsb + o_part);
    int*    eidx    = (int*)(wsb + o_eidx);
    ushort* w1t     = (ushort*)(wsb + o_w1);
    ushort* w2t     = (ushort*)(wsb + o_w2);
    ushort* xb      = (ushort*)(wsb + o_xb);
    ushort* hb      = (ushort*)(wsb + o_hb);
    ushort* Ynb     = (ushort*)(wsb + o_ynb);
    float*  Ys      = (float*)(wsb + o_ys);
    float*  pooled  = (float*)(wsb + o_pool);
    float*  cnt     = pooled + 16 * HID;

    hipMemsetAsync(degi, 0, (size_t)n_nodes * 4, stream);
    hipMemsetAsync(pooled, 0, (size_t)(16 * HID + 16) * 4, stream);

    // ---- CSR build (by dst): histogram -> hierarchical scan -> fill
    degi_kernel<<<(n_edges + 255) / 256, 256, 0, stream>>>(dst, degi, n_edges);
    psum_kernel<<<nb, 256, 0, stream>>>(degi, partials, n_nodes);
    pscan_kernel<<<1, 64, 0, stream>>>(partials, off, nb, n_nodes);
    scan2_kernel<<<nb, 256, 0, stream>>>(degi, partials, off, cursor, n_nodes);
    fill_kernel<<<(n_edges + 255) / 256, 256, 0, stream>>>(src, dst, cursor, eidx, n_edges);

    // ---- convert x to bf16; pack+transpose weights to bf16 B^T
    int n4 = n_nodes * in_dim / 4;
    cvt_kernel<<<(n4 + 255) / 256, 256, 0, stream>>>(x, xb, n4);
    packT_kernel<<<(NCOL * in_dim + 255) / 256, 256, 0, stream>>>(W1n, W1s, w1t, in_dim);
    packT_kernel<<<(NCOL * HID + 255) / 256, 256, 0, stream>>>(W2n, W2s, w2t, HID);

    dim3 gemm_grid(NCOL / 128, Mpad / 128);
    int gather_blocks = (n_nodes + 3) / 4;

    // ---- layer 1
    gemm_mfma<<<gemm_grid, 256, 0, stream>>>(xb, w1t, Ynb, Ys, in_dim);
    gather_kernel<<<gather_blocks, 256, 0, stream>>>(Ynb, Ys, off, eidx, b1, hb, n_nodes);

    // ---- layer 2
    gemm_mfma<<<gemm_grid, 256, 0, stream>>>(hb, w2t, Ynb, Ys, HID);
    gather_kernel<<<gather_blocks, 256, 0, stream>>>(Ynb, Ys, off, eidx, b2, hb, n_nodes);

    // ---- pool + head
    pool_kernel<<<(n_nodes + 63) / 64, 256, 0, stream>>>(hb, batch, pooled, cnt, n_nodes);
    head_kernel<<<16, 128, 0, stream>>>(pooled, cnt, fc1w, fc1b, fc2w, fc2b, out);
}

// Round 6
// 231.619 us; speedup vs baseline: 6.4027x; 1.0875x over previous
//
#include <hip/hip_runtime.h>
#include <hip/hip_bf16.h>

// GraphSAGE forward. R5: 64x128 GEMM tile (3 blocks/CU), unified bf16 Y,
// gather unroll-4, fused prep kernel (cvt + packT x2 + degree histogram).
// Per layer: Y = H_in @ [Wn | Ws] (bf16, Mpad x 512), then fused gather:
//   h_out[v] = bf16( relu( (sum_e Yn[eidx[e]]) / max(deg,1) + Ys[v] + b ) )

#define HID 256
#define NCOL 512

typedef __bf16 bf16x8 __attribute__((ext_vector_type(8)));
typedef float floatx4 __attribute__((ext_vector_type(4)));
typedef unsigned int u32;
typedef const u32 __attribute__((address_space(1)))* gp_t;
typedef u32 __attribute__((address_space(3)))* lp_t;

__device__ __forceinline__ ushort f2bf(float f) {   // round-to-nearest-even
    unsigned u = __float_as_uint(f);
    u += 0x7fffu + ((u >> 16) & 1u);
    return (ushort)(u >> 16);
}
__device__ __forceinline__ float bf2f(ushort b) {
    return __uint_as_float(((unsigned)b) << 16);
}

// ---------------- fused prep: [cvt x->bf16 | packT W1 | packT W2 | degree histogram]
__device__ __forceinline__ void packT_work(const float* __restrict__ Wn,
                                           const float* __restrict__ Ws,
                                           ushort* __restrict__ WT, int K, int gid) {
    if (gid >= NCOL * K) return;
    int n = gid / K, k = gid - n * K;
    float v = (n < HID) ? Wn[k * HID + n] : Ws[k * HID + (n - HID)];
    WT[gid] = f2bf(v);
}

__global__ void prep_kernel(const float* __restrict__ x, ushort* __restrict__ xb, int n4,
                            const float* __restrict__ W1n, const float* __restrict__ W1s,
                            ushort* __restrict__ w1t, int K1,
                            const float* __restrict__ W2n, const float* __restrict__ W2s,
                            ushort* __restrict__ w2t, int K2,
                            const int* __restrict__ dst, int* __restrict__ degi, int n_edges,
                            int nb_cvt, int nb_w1, int nb_w2) {
    int bx = blockIdx.x, t = threadIdx.x;
    if (bx < nb_cvt) {
        int i = bx * 256 + t;
        if (i < n4) {
            float4 v = ((const float4*)x)[i];
            ushort4 o;
            o.x = f2bf(v.x); o.y = f2bf(v.y); o.z = f2bf(v.z); o.w = f2bf(v.w);
            ((ushort4*)xb)[i] = o;
        }
    } else if (bx < nb_cvt + nb_w1) {
        packT_work(W1n, W1s, w1t, K1, (bx - nb_cvt) * 256 + t);
    } else if (bx < nb_cvt + nb_w1 + nb_w2) {
        packT_work(W2n, W2s, w2t, K2, (bx - nb_cvt - nb_w1) * 256 + t);
    } else {
        int e = (bx - nb_cvt - nb_w1 - nb_w2) * 256 + t;
        if (e < n_edges) atomicAdd(&degi[dst[e]], 1);
    }
}

// ---------------- scan phase 1: per-256-chunk sums
__global__ __launch_bounds__(256) void psum_kernel(const int* __restrict__ degi,
                                                   int* __restrict__ partials, int n) {
    int t = threadIdx.x;
    int i = blockIdx.x * 256 + t;
    int v = (i < n) ? degi[i] : 0;
#pragma unroll
    for (int d = 1; d < 64; d <<= 1) v += __shfl_xor(v, d, 64);
    __shared__ int wsum[4];
    if ((t & 63) == 0) wsum[t >> 6] = v;
    __syncthreads();
    if (t == 0) partials[blockIdx.x] = wsum[0] + wsum[1] + wsum[2] + wsum[3];
}

// ---------------- scan phase 2: 1-wave exclusive scan of partials (in place)
__global__ __launch_bounds__(64) void pscan_kernel(int* __restrict__ partials,
                                                   int* __restrict__ off, int nb, int n) {
    int lane = threadIdx.x;
    int carry = 0;
    for (int base = 0; base < nb; base += 256) {
        int i0 = base + lane * 4;
        int v0 = (i0 + 0 < nb) ? partials[i0 + 0] : 0;
        int v1 = (i0 + 1 < nb) ? partials[i0 + 1] : 0;
        int v2 = (i0 + 2 < nb) ? partials[i0 + 2] : 0;
        int v3 = (i0 + 3 < nb) ? partials[i0 + 3] : 0;
        int local = v0 + v1 + v2 + v3;
        int s = local;
#pragma unroll
        for (int d = 1; d < 64; d <<= 1) {
            int t = __shfl_up(s, d, 64);
            if (lane >= d) s += t;
        }
        int excl = carry + s - local;
        if (i0 + 0 < nb) partials[i0 + 0] = excl;
        excl += v0;
        if (i0 + 1 < nb) partials[i0 + 1] = excl;
        excl += v1;
        if (i0 + 2 < nb) partials[i0 + 2] = excl;
        excl += v2;
        if (i0 + 3 < nb) partials[i0 + 3] = excl;
        carry += __shfl(s, 63, 64);
    }
    if (lane == 0) off[n] = carry;
}

// ---------------- scan phase 3: per-chunk rescan + chunk offset -> off, cursor
__global__ __launch_bounds__(256) void scan2_kernel(const int* __restrict__ degi,
                                                    const int* __restrict__ partials,
                                                    int* __restrict__ off,
                                                    int* __restrict__ cursor, int n) {
    int t = threadIdx.x, lane = t & 63, w = t >> 6;
    int i = blockIdx.x * 256 + t;
    int v = (i < n) ? degi[i] : 0;
    int s = v;
#pragma unroll
    for (int d = 1; d < 64; d <<= 1) {
        int u = __shfl_up(s, d, 64);
        if (lane >= d) s += u;
    }
    __shared__ int wsum[4];
    if (lane == 63) wsum[w] = s;
    __syncthreads();
    int woff = 0;
    for (int k = 0; k < w; ++k) woff += wsum[k];
    int excl = partials[blockIdx.x] + woff + s - v;
    if (i < n) { off[i] = excl; cursor[i] = excl; }
}

// ---------------- CSR fill: eidx[pos] = src[e], pos = cursor[dst[e]]++
__global__ void fill_kernel(const int* __restrict__ src, const int* __restrict__ dst,
                            int* __restrict__ cursor, int* __restrict__ eidx, int n_edges) {
    int e = blockIdx.x * 256 + threadIdx.x;
    if (e < n_edges) {
        int p = atomicAdd(&cursor[dst[e]], 1);
        eidx[p] = src[e];
    }
}

// ---------------- bf16 MFMA GEMM: Y[Mpad,512] = A[Mpad,K] @ BT[512,K]^T (bf16 out)
// 64x128 block tile, 4 waves (2x2 of 32x64), BK=64, double-buffered global_load_lds,
// XOR swizzle on 16B units within each 128B LDS row. 48 KB LDS -> 3 blocks/CU.
__global__ __launch_bounds__(256) void gemm_mfma(const ushort* __restrict__ A,
                                                 const ushort* __restrict__ BT,
                                                 ushort* __restrict__ Y, int K) {
    __shared__ ushort As[2][64 * 64];
    __shared__ ushort Bs[2][128 * 64];
    int tid = threadIdx.x;
    int w = tid >> 6, lane = tid & 63;
    int quad = lane >> 4, r16 = lane & 15;
    int m0 = blockIdx.y * 64, n0 = blockIdx.x * 128;
    int wm = (w >> 1) * 32, wn = (w & 1) * 64;

    // staging slots (16B each): A 512 slots (2/thread), B 1024 slots (4/thread)
    int arow[2], agu[2], brow[4], bgu[4];
#pragma unroll
    for (int rr = 0; rr < 2; ++rr) {
        int idx = rr * 256 + tid;
        arow[rr] = idx >> 3;
        agu[rr] = (idx & 7) ^ (arow[rr] & 7);
    }
#pragma unroll
    for (int rr = 0; rr < 4; ++rr) {
        int idx = rr * 256 + tid;
        brow[rr] = idx >> 3;
        bgu[rr] = (idx & 7) ^ (brow[rr] & 7);
    }

    auto stage = [&](int buf, int k0) {
#pragma unroll
        for (int rr = 0; rr < 2; ++rr) {
            const ushort* ga = A + (size_t)(m0 + arow[rr]) * K + k0 + agu[rr] * 8;
            ushort* la = As[buf] + (size_t)(rr * 256 + w * 64) * 8;   // wave-uniform base
            __builtin_amdgcn_global_load_lds((gp_t)(const void*)ga, (lp_t)(void*)la, 16, 0, 0);
        }
#pragma unroll
        for (int rr = 0; rr < 4; ++rr) {
            const ushort* gb = BT + (size_t)(n0 + brow[rr]) * K + k0 + bgu[rr] * 8;
            ushort* lb = Bs[buf] + (size_t)(rr * 256 + w * 64) * 8;
            __builtin_amdgcn_global_load_lds((gp_t)(const void*)gb, (lp_t)(void*)lb, 16, 0, 0);
        }
    };

    floatx4 acc[2][4];
#pragma unroll
    for (int i = 0; i < 2; ++i)
#pragma unroll
        for (int j = 0; j < 4; ++j) acc[i][j] = (floatx4){0.f, 0.f, 0.f, 0.f};

    const int nk = K >> 6;
    stage(0, 0);
    for (int t = 0; t < nk; ++t) {
        int cb = t & 1;
        __syncthreads();                      // drains prefetch into buf cb
        if (t + 1 < nk) stage(cb ^ 1, (t + 1) << 6);   // overlaps compute below
        const ushort* Ab = As[cb];
        const ushort* Bb = Bs[cb];
#pragma unroll
        for (int s = 0; s < 2; ++s) {
            bf16x8 a[2], b[4];
#pragma unroll
            for (int i = 0; i < 2; ++i) {
                int row = wm + i * 16 + r16;
                int au = (s * 4 + quad) ^ (row & 7);
                a[i] = *(const bf16x8*)(Ab + row * 64 + au * 8);
            }
#pragma unroll
            for (int j = 0; j < 4; ++j) {
                int row = wn + j * 16 + r16;
                int bu = (s * 4 + quad) ^ (row & 7);
                b[j] = *(const bf16x8*)(Bb + row * 64 + bu * 8);
            }
#pragma unroll
            for (int i = 0; i < 2; ++i)
#pragma unroll
                for (int j = 0; j < 4; ++j)
                    acc[i][j] = __builtin_amdgcn_mfma_f32_16x16x32_bf16(a[i], b[j], acc[i][j], 0, 0, 0);
        }
    }
    // epilogue: C/D layout col=lane&15, row=quad*4+reg; bf16 store
#pragma unroll
    for (int i = 0; i < 2; ++i)
#pragma unroll
        for (int j = 0; j < 4; ++j) {
            int col = n0 + wn + j * 16 + r16;
#pragma unroll
            for (int rg = 0; rg < 4; ++rg) {
                int row = m0 + wm + i * 16 + quad * 4 + rg;
                Y[(size_t)row * NCOL + col] = f2bf(acc[i][j][rg]);
            }
        }
}

// ---------------- fused gather + combine: one 64-lane wave per node, unroll-4
__global__ __launch_bounds__(256) void gather_kernel(const ushort* __restrict__ Y,
                                                     const int* __restrict__ off,
                                                     const int* __restrict__ eidx,
                                                     const float* __restrict__ bias,
                                                     ushort* __restrict__ h, int n_nodes) {
    int tid = threadIdx.x;
    int v = blockIdx.x * 4 + (tid >> 6);
    if (v >= n_nodes) return;
    int q4 = (tid & 63) << 2;
    int e0 = off[v], e1 = off[v + 1];
    ushort4 sv = *(const ushort4*)(Y + (size_t)v * NCOL + HID + q4);   // self (bf16)
    float4 b = *(const float4*)(bias + q4);
    float4 a0 = make_float4(0.f, 0.f, 0.f, 0.f), a1 = a0, a2 = a0, a3 = a0;
    int e = e0;
    for (; e + 3 < e1; e += 4) {
        int s0 = eidx[e], s1 = eidx[e + 1], s2 = eidx[e + 2], s3 = eidx[e + 3];
        ushort4 y0 = *(const ushort4*)(Y + (size_t)s0 * NCOL + q4);
        ushort4 y1 = *(const ushort4*)(Y + (size_t)s1 * NCOL + q4);
        ushort4 y2 = *(const ushort4*)(Y + (size_t)s2 * NCOL + q4);
        ushort4 y3 = *(const ushort4*)(Y + (size_t)s3 * NCOL + q4);
        a0.x += bf2f(y0.x); a0.y += bf2f(y0.y); a0.z += bf2f(y0.z); a0.w += bf2f(y0.w);
        a1.x += bf2f(y1.x); a1.y += bf2f(y1.y); a1.z += bf2f(y1.z); a1.w += bf2f(y1.w);
        a2.x += bf2f(y2.x); a2.y += bf2f(y2.y); a2.z += bf2f(y2.z); a2.w += bf2f(y2.w);
        a3.x += bf2f(y3.x); a3.y += bf2f(y3.y); a3.z += bf2f(y3.z); a3.w += bf2f(y3.w);
    }
    for (; e < e1; ++e) {
        ushort4 y = *(const ushort4*)(Y + (size_t)eidx[e] * NCOL + q4);
        a0.x += bf2f(y.x); a0.y += bf2f(y.y); a0.z += bf2f(y.z); a0.w += bf2f(y.w);
    }
    float invd = 1.0f / fmaxf((float)(e1 - e0), 1.0f);
    ushort4 r;
    r.x = f2bf(fmaxf((a0.x + a1.x + a2.x + a3.x) * invd + bf2f(sv.x) + b.x, 0.f));
    r.y = f2bf(fmaxf((a0.y + a1.y + a2.y + a3.y) * invd + bf2f(sv.y) + b.y, 0.f));
    r.z = f2bf(fmaxf((a0.z + a1.z + a2.z + a3.z) * invd + bf2f(sv.z) + b.z, 0.f));
    r.w = f2bf(fmaxf((a0.w + a1.w + a2.w + a3.w) * invd + bf2f(sv.w) + b.w, 0.f));
    *(ushort4*)(h + (size_t)v * HID + q4) = r;
}

// ---------------- segmented mean-pool (batch sorted), bf16 in, fp32 accumulate
__global__ void pool_kernel(const ushort* __restrict__ h, const int* __restrict__ batch,
                            float* __restrict__ pooled, float* __restrict__ cnt, int n_nodes) {
    int f = threadIdx.x;                     // 256 features
    int v0 = blockIdx.x * 64;
    int vend = min(v0 + 64, n_nodes);
    if (v0 >= n_nodes) return;
    int cur = batch[v0];
    float acc = 0.f, ac = 0.f;
    for (int v = v0; v < vend; ++v) {
        int g = batch[v];
        if (g != cur) {
            atomicAdd(&pooled[cur * HID + f], acc);
            if (f == 0) atomicAdd(&cnt[cur], ac);
            acc = 0.f; ac = 0.f; cur = g;
        }
        acc += bf2f(h[(size_t)v * HID + f]);
        ac += 1.0f;
    }
    atomicAdd(&pooled[cur * HID + f], acc);
    if (f == 0) atomicAdd(&cnt[cur], ac);
}

// ---------------- MLP head: out[g] = relu(pooled_mean @ fc1w + fc1b) @ fc2w + fc2b
__global__ void head_kernel(const float* __restrict__ pooled, const float* __restrict__ cnt,
                            const float* __restrict__ fc1w, const float* __restrict__ fc1b,
                            const float* __restrict__ fc2w, const float* __restrict__ fc2b,
                            float* __restrict__ out) {
    int g = blockIdx.x, j = threadIdx.x;     // 128 threads
    __shared__ float p[256];
    __shared__ float hid[128];
    float inv = 1.0f / fmaxf(cnt[g], 1.0f);
    p[j] = pooled[g * HID + j] * inv;
    p[j + 128] = pooled[g * HID + 128 + j] * inv;
    __syncthreads();
    float a = fc1b[j];
    for (int f = 0; f < 256; ++f) a += p[f] * fc1w[f * 128 + j];
    hid[j] = fmaxf(a, 0.f);
    __syncthreads();
    if (j < 2) {
        float o = fc2b[j];
        for (int t = 0; t < 128; ++t) o += hid[t] * fc2w[t * 2 + j];
        out[g * 2 + j] = o;
    }
}

extern "C" void kernel_launch(void* const* d_in, const int* in_sizes, int n_in,
                              void* d_out, int out_size, void* d_ws, size_t ws_size,
                              hipStream_t stream) {
    const float* x    = (const float*)d_in[0];
    const int*   ei   = (const int*)d_in[1];
    const int*   batch= (const int*)d_in[2];
    const float* W1n  = (const float*)d_in[3];
    const float* W1s  = (const float*)d_in[4];
    const float* b1   = (const float*)d_in[5];
    const float* W2n  = (const float*)d_in[6];
    const float* W2s  = (const float*)d_in[7];
    const float* b2   = (const float*)d_in[8];
    const float* fc1w = (const float*)d_in[9];
    const float* fc1b = (const float*)d_in[10];
    const float* fc2w = (const float*)d_in[11];
    const float* fc2b = (const float*)d_in[12];
    float* out = (float*)d_out;

    const int n_nodes = in_sizes[2];
    const int n_edges = in_sizes[1] / 2;
    const int in_dim  = in_sizes[0] / n_nodes;   // 512
    const int Mpad    = (n_nodes + 63) & ~63;    // 20032
    const int nb      = (n_nodes + 255) / 256;   // scan chunks
    const int* src = ei;
    const int* dst = ei + n_edges;

    // workspace layout, 256B-aligned slices
    char* wsb = (char*)d_ws;
    size_t cur = 0;
    auto alloc = [&](size_t nbytes) { size_t o = cur; cur = (cur + nbytes + 255) & ~(size_t)255; return o; };
    size_t o_degi = alloc((size_t)n_nodes * 4);
    size_t o_off  = alloc((size_t)(n_nodes + 1) * 4);
    size_t o_cur  = alloc((size_t)n_nodes * 4);
    size_t o_part = alloc((size_t)nb * 4);
    size_t o_eidx = alloc((size_t)n_edges * 4);
    size_t o_w1   = alloc((size_t)NCOL * in_dim * 2);    // W1catT bf16 [512][512]
    size_t o_w2   = alloc((size_t)NCOL * HID * 2);       // W2catT bf16 [512][256]
    size_t o_xb   = alloc((size_t)Mpad * in_dim * 2);    // x bf16, padded rows
    size_t o_hb   = alloc((size_t)Mpad * HID * 2);       // h bf16, padded rows
    size_t o_y    = alloc((size_t)Mpad * NCOL * 2);      // Y bf16 [Yn|Ys]
    size_t o_pool = alloc((size_t)16 * HID * 4 + 16 * 4);
    (void)ws_size;

    int*    degi    = (int*)(wsb + o_degi);
    int*    off     = (int*)(wsb + o_off);
    int*    cursor  = (int*)(wsb + o_cur);
    int*    partials= (int*)(wsb + o_part);
    int*    eidx    = (int*)(wsb + o_eidx);
    ushort* w1t     = (ushort*)(wsb + o_w1);
    ushort* w2t     = (ushort*)(wsb + o_w2);
    ushort* xb      = (ushort*)(wsb + o_xb);
    ushort* hb      = (ushort*)(wsb + o_hb);
    ushort* Y       = (ushort*)(wsb + o_y);
    float*  pooled  = (float*)(wsb + o_pool);
    float*  cnt     = pooled + 16 * HID;

    hipMemsetAsync(degi, 0, (size_t)n_nodes * 4, stream);
    hipMemsetAsync(pooled, 0, (size_t)(16 * HID + 16) * 4, stream);

    // ---- fused prep: cvt | packT W1 | packT W2 | degree histogram
    int n4 = n_nodes * in_dim / 4;
    int nb_cvt = (n4 + 255) / 256;
    int nb_w1  = (NCOL * in_dim + 255) / 256;
    int nb_w2  = (NCOL * HID + 255) / 256;
    int nb_deg = (n_edges + 255) / 256;
    prep_kernel<<<nb_cvt + nb_w1 + nb_w2 + nb_deg, 256, 0, stream>>>(
        x, xb, n4, W1n, W1s, w1t, in_dim, W2n, W2s, w2t, HID,
        dst, degi, n_edges, nb_cvt, nb_w1, nb_w2);

    // ---- CSR build: hierarchical scan -> fill
    psum_kernel<<<nb, 256, 0, stream>>>(degi, partials, n_nodes);
    pscan_kernel<<<1, 64, 0, stream>>>(partials, off, nb, n_nodes);
    scan2_kernel<<<nb, 256, 0, stream>>>(degi, partials, off, cursor, n_nodes);
    fill_kernel<<<(n_edges + 255) / 256, 256, 0, stream>>>(src, dst, cursor, eidx, n_edges);

    dim3 gemm_grid(NCOL / 128, Mpad / 64);
    int gather_blocks = (n_nodes + 3) / 4;

    // ---- layer 1
    gemm_mfma<<<gemm_grid, 256, 0, stream>>>(xb, w1t, Y, in_dim);
    gather_kernel<<<gather_blocks, 256, 0, stream>>>(Y, off, eidx, b1, hb, n_nodes);

    // ---- layer 2
    gemm_mfma<<<gemm_grid, 256, 0, stream>>>(hb, w2t, Y, HID);
    gather_kernel<<<gather_blocks, 256, 0, stream>>>(Y, off, eidx, b2, hb, n_nodes);

    // ---- pool + head
    pool_kernel<<<(n_nodes + 63) / 64, 256, 0, stream>>>(hb, batch, pooled, cnt, n_nodes);
    head_kernel<<<16, 128, 0, stream>>>(pooled, cnt, fc1w, fc1b, fc2w, fc2b, out);
}